// Round 12
// baseline (466.947 us; speedup 1.0000x reference)
//
#include <hip/hip_runtime.h>

#define NNODE 1000
#define D 64
#define K_TOP 20
#define NROWS 32000   // B*N = 32*1000
#define GCN_ROWS 16
#define NPART (NROWS / GCN_ROWS)   // 2000 BN partials
typedef unsigned long long ull;

// ---------------- inverse norms (f64) ----------------
__global__ void norms_kernel(const float* __restrict__ e0, const float* __restrict__ e1,
                             const float* __restrict__ e2, double* __restrict__ inv_nrm) {
    int g = blockIdx.y;
    const float* e = (g == 0) ? e0 : ((g == 1) ? e1 : e2);
    int j = blockIdx.x * 256 + threadIdx.x;
    if (j < NNODE) {
        double s = 0.0;
        #pragma unroll
        for (int k = 0; k < D; ++k) { double v = (double)e[j * D + k]; s += v * v; }
        inv_nrm[g * NNODE + j] = 1.0 / sqrt(s);
    }
}

__device__ __forceinline__ ull packkey(double cosv, int j) {
    ull b = (ull)__double_as_longlong(cosv);
    ull k = (b >> 63) ? ~b : (b | 0x8000000000000000ULL);
    return (k & ~1023ULL) | (ull)(1023 - j);
}

__device__ __forceinline__ int cnt20(const ull* pl, ull v) {
    const ulonglong2* p2 = (const ulonglong2*)pl;
    int cnt = 0;
    #pragma unroll
    for (int m = 0; m < 10; ++m) {
        ulonglong2 ab = p2[m];
        cnt += (ab.x > v) ? 1 : 0;
        cnt += (ab.y > v) ? 1 : 0;
    }
    return cnt;
}

// ---------------- fused: topk (blocks 0..2999, R11-verified body) + rowgemm60 (blocks 3000..6999) ----
// LDS overlaid via one char buffer (topk 13.2 KB / rowgemm 17.3 KB).
__global__ void __launch_bounds__(256, 2)
topk_gemm_kernel(const float* __restrict__ e0, const float* __restrict__ e1,
                 const float* __restrict__ e2, const double* __restrict__ inv_nrm,
                 int* __restrict__ idxM, int* __restrict__ idxP,
                 int* __restrict__ idxN, float* __restrict__ idxf_out,
                 const float* __restrict__ X, const float* __restrict__ W,
                 const float* __restrict__ bias, float* __restrict__ A) {
    __shared__ __align__(16) char smem[17280];
    int blk = blockIdx.x;
    int tid = threadIdx.x;

    if (blk < 3000) {
        // ---- topk (identical math to R11) ----
        float* srow = (float*)smem;                 // 256 B
        ull* skey = (ull*)(smem + 256);             // 8 KB
        ull* sw16 = (ull*)(smem + 8448);            // 2.5 KB
        ull* m8   = (ull*)(smem + 11008);           // 1.25 KB
        ull* m4   = (ull*)(smem + 12288);           // 640 B
        ull* m2   = (ull*)(smem + 12928);           // 320 B

        int g = blk / 1000;
        int i = blk - g * 1000;
        const float* emb = (g == 0) ? e0 : ((g == 1) ? e1 : e2);
        int* idx_out = (g == 0) ? idxM : ((g == 1) ? idxP : idxN);
        const double* inv = inv_nrm + g * NNODE;

        int w = tid >> 6, l = tid & 63;
        int rowq = tid >> 2;
        int s = tid & 3;

        if (tid < D) srow[tid] = emb[i * D + tid];
        __syncthreads();

        double inv_i = inv[i];
        const float4* sr4 = (const float4*)srow + s * 4;

        #pragma unroll 2
        for (int p = 0; p < 16; ++p) {
            int j = p * 64 + rowq;
            int jc = (j < NNODE) ? j : 0;
            const float4* ej = (const float4*)(emb + (size_t)jc * D) + s * 4;
            double acc = 0.0;
            #pragma unroll
            for (int q = 0; q < 4; ++q) {
                float4 v = ej[q];
                float4 r = sr4[q];
                acc = fma((double)v.x, (double)r.x, acc);
                acc = fma((double)v.y, (double)r.y, acc);
                acc = fma((double)v.z, (double)r.z, acc);
                acc = fma((double)v.w, (double)r.w, acc);
            }
            acc += __shfl_xor(acc, 1, 64);
            acc += __shfl_xor(acc, 2, 64);
            if (s == 0) {
                double cosv = acc * inv_i * inv[jc];
                skey[j] = (j < NNODE) ? packkey(cosv, j) : 0ULL;
            }
        }
        __syncthreads();

        {
            const ulonglong2* base = (const ulonglong2*)(skey + (w << 8));
            ull k0 = skey[(w << 8) + l];
            ull k1 = skey[(w << 8) + 64 + l];
            ull k2 = skey[(w << 8) + 128 + l];
            ull k3 = skey[(w << 8) + 192 + l];
            int n0 = 0, n1 = 0, n2 = 0, n3 = 0;
            #pragma unroll 8
            for (int m = 0; m < 32; ++m) {
                ulonglong2 a0 = base[m];
                ulonglong2 a1 = base[32 + m];
                ulonglong2 a2 = base[64 + m];
                ulonglong2 a3 = base[96 + m];
                n0 += (a0.x > k0) ? 1 : 0;  n0 += (a0.y > k0) ? 1 : 0;
                n1 += (a1.x > k1) ? 1 : 0;  n1 += (a1.y > k1) ? 1 : 0;
                n2 += (a2.x > k2) ? 1 : 0;  n2 += (a2.y > k2) ? 1 : 0;
                n3 += (a3.x > k3) ? 1 : 0;  n3 += (a3.y > k3) ? 1 : 0;
            }
            if (n0 < K_TOP) sw16[((w << 2) + 0) * K_TOP + n0] = k0;
            if (n1 < K_TOP) sw16[((w << 2) + 1) * K_TOP + n1] = k1;
            if (n2 < K_TOP) sw16[((w << 2) + 2) * K_TOP + n2] = k2;
            if (n3 < K_TOP) sw16[((w << 2) + 3) * K_TOP + n3] = k3;
        }
        __syncthreads();

        {
            int e = tid;
            int lw = e / K_TOP, r = e % K_TOP;
            ull v = sw16[e];
            int rank = r + cnt20(sw16 + (lw ^ 1) * K_TOP, v);
            if (rank < K_TOP) m8[(lw >> 1) * K_TOP + rank] = v;
            if (tid < 64) {
                int e2 = 256 + tid;
                int lw2 = e2 / K_TOP, r2 = e2 % K_TOP;
                ull v2 = sw16[e2];
                int rank2 = r2 + cnt20(sw16 + (lw2 ^ 1) * K_TOP, v2);
                if (rank2 < K_TOP) m8[(lw2 >> 1) * K_TOP + rank2] = v2;
            }
        }
        __syncthreads();
        if (tid < 160) {
            int lw = tid / K_TOP, r = tid % K_TOP;
            ull v = m8[tid];
            int rank = r + cnt20(m8 + (lw ^ 1) * K_TOP, v);
            if (rank < K_TOP) m4[(lw >> 1) * K_TOP + rank] = v;
        }
        __syncthreads();
        if (tid < 80) {
            int lw = tid / K_TOP, r = tid % K_TOP;
            ull v = m4[tid];
            int rank = r + cnt20(m4 + (lw ^ 1) * K_TOP, v);
            if (rank < K_TOP) m2[(lw >> 1) * K_TOP + rank] = v;
        }
        __syncthreads();
        if (tid < 40) {
            int lw = tid / K_TOP, r = tid % K_TOP;
            ull v = m2[tid];
            int rank = r + cnt20(m2 + (lw ^ 1) * K_TOP, v);
            if (rank < K_TOP) {
                int id = 1023 - (int)(v & 1023ULL);
                idx_out[i * K_TOP + rank] = id;
                if (g == 0) idxf_out[i * K_TOP + rank] = (float)id;
            }
        }
    } else {
        // ---- rowgemm K=60 (identical math to R11) ----
        const int K = 60;
        float* Ws = (float*)smem;               // 15360 B
        float* xs = (float*)(smem + 15360);     // 8*60*4 = 1920 B
        int rb = blk - 3000;
        for (int e = tid; e < K * D; e += 256) Ws[e] = W[e];
        int base_row = rb * 8;
        for (int e = tid; e < 8 * K; e += 256) {
            int r = e / K, k = e % K;
            xs[r * K + k] = X[(size_t)(base_row + r) * K + k];
        }
        __syncthreads();
        int lr = tid >> 6, c = tid & 63;
        #pragma unroll
        for (int rep = 0; rep < 2; ++rep) {
            int r = lr * 2 + rep;
            float acc = bias[c];
            #pragma unroll
            for (int k = 0; k < K; ++k) acc = fmaf(xs[r * K + k], Ws[k * D + c], acc);
            A[(size_t)(base_row + r) * D + c] = acc;
        }
    }
}

// ---------------- GCN gather-mean-relu (float4) + inline BN partial sums ----------------
// 16 rows/block; thread = (row rr, col-quad q). Gather adds in same per-column
// order as before -> t values bit-identical. f64 column partials reduced by
// shfl (rows within wave) + LDS (across 4 waves), fixed order -> deterministic.
__device__ __forceinline__ void gcn_bn_body(const float* __restrict__ h, const int* __restrict__ idx,
                                            const float* __restrict__ emb, float* __restrict__ t_out,
                                            float* __restrict__ x_out,
                                            double* __restrict__ psum, double* __restrict__ psq,
                                            int blk) {
    __shared__ int nbrs[GCN_ROWS][K_TOP];
    __shared__ double4 shs[4][16], shq[4][16];
    int tid = threadIdx.x;
    int rr = tid >> 4, q = tid & 15;
    int base_row = blk * GCN_ROWS;
    for (int e = tid; e < GCN_ROWS * K_TOP; e += 256) {
        int r2 = e / K_TOP, tt = e % K_TOP;
        int node = (base_row + r2) % NNODE;
        nbrs[r2][tt] = idx[node * K_TOP + tt];
    }
    __syncthreads();
    int row = base_row + rr;
    int b = row / NNODE, i = row - b * NNODE;
    const float* hb = h + (size_t)b * NNODE * D;
    float4 s4 = make_float4(0.f, 0.f, 0.f, 0.f);
    #pragma unroll
    for (int t = 0; t < K_TOP; ++t) {
        float4 v = *(const float4*)(hb + (size_t)nbrs[rr][t] * D + q * 4);
        s4.x += v.x; s4.y += v.y; s4.z += v.z; s4.w += v.w;
    }
    const float inv20 = 1.0f / 20.0f;
    float4 y4;
    y4.x = fmaxf(s4.x * inv20, 0.f);
    y4.y = fmaxf(s4.y * inv20, 0.f);
    y4.z = fmaxf(s4.z * inv20, 0.f);
    y4.w = fmaxf(s4.w * inv20, 0.f);
    if (x_out) *(float4*)(x_out + (size_t)row * D + q * 4) = y4;
    float4 e4 = *(const float4*)(emb + (size_t)i * D + q * 4);
    float4 t4 = make_float4(y4.x * e4.x, y4.y * e4.y, y4.z * e4.z, y4.w * e4.w);
    *(float4*)(t_out + (size_t)row * D + q * 4) = t4;

    // f64 column partials over the block's 16 rows
    double s0 = t4.x, s1 = t4.y, s2 = t4.z, s3 = t4.w;
    double q0 = s0 * s0, q1 = s1 * s1, q2 = s2 * s2, q3 = s3 * s3;
    s0 += __shfl_xor(s0, 16, 64);  s0 += __shfl_xor(s0, 32, 64);
    s1 += __shfl_xor(s1, 16, 64);  s1 += __shfl_xor(s1, 32, 64);
    s2 += __shfl_xor(s2, 16, 64);  s2 += __shfl_xor(s2, 32, 64);
    s3 += __shfl_xor(s3, 16, 64);  s3 += __shfl_xor(s3, 32, 64);
    q0 += __shfl_xor(q0, 16, 64);  q0 += __shfl_xor(q0, 32, 64);
    q1 += __shfl_xor(q1, 16, 64);  q1 += __shfl_xor(q1, 32, 64);
    q2 += __shfl_xor(q2, 16, 64);  q2 += __shfl_xor(q2, 32, 64);
    q3 += __shfl_xor(q3, 16, 64);  q3 += __shfl_xor(q3, 32, 64);
    int wv = tid >> 6;
    if (((tid >> 4) & 3) == 0) {   // local row 0 of each wave
        shs[wv][q] = make_double4(s0, s1, s2, s3);
        shq[wv][q] = make_double4(q0, q1, q2, q3);
    }
    __syncthreads();
    if (tid < 16) {
        double a0 = shs[0][tid].x + shs[1][tid].x + shs[2][tid].x + shs[3][tid].x;
        double a1 = shs[0][tid].y + shs[1][tid].y + shs[2][tid].y + shs[3][tid].y;
        double a2 = shs[0][tid].z + shs[1][tid].z + shs[2][tid].z + shs[3][tid].z;
        double a3 = shs[0][tid].w + shs[1][tid].w + shs[2][tid].w + shs[3][tid].w;
        psum[(size_t)blk * D + tid * 4 + 0] = a0;
        psum[(size_t)blk * D + tid * 4 + 1] = a1;
        psum[(size_t)blk * D + tid * 4 + 2] = a2;
        psum[(size_t)blk * D + tid * 4 + 3] = a3;
        double b0 = shq[0][tid].x + shq[1][tid].x + shq[2][tid].x + shq[3][tid].x;
        double b1 = shq[0][tid].y + shq[1][tid].y + shq[2][tid].y + shq[3][tid].y;
        double b2 = shq[0][tid].z + shq[1][tid].z + shq[2][tid].z + shq[3][tid].z;
        double b3 = shq[0][tid].w + shq[1][tid].w + shq[2][tid].w + shq[3][tid].w;
        psq[(size_t)blk * D + tid * 4 + 0] = b0;
        psq[(size_t)blk * D + tid * 4 + 1] = b1;
        psq[(size_t)blk * D + tid * 4 + 2] = b2;
        psq[(size_t)blk * D + tid * 4 + 3] = b3;
    }
}

__global__ void gcn_bn_kernel(const float* __restrict__ h, const int* __restrict__ idx,
                              const float* __restrict__ emb, float* __restrict__ t_out,
                              float* __restrict__ x_out,
                              double* __restrict__ psum, double* __restrict__ psq) {
    gcn_bn_body(h, idx, emb, t_out, x_out, psum, psq, blockIdx.x);
}

__global__ void gcn_bn_dual_kernel(const float* __restrict__ hA, const int* __restrict__ idxA,
                                   const float* __restrict__ embA, float* __restrict__ tA,
                                   float* __restrict__ xA,
                                   const float* __restrict__ hB, const int* __restrict__ idxB,
                                   const float* __restrict__ embB, float* __restrict__ tB,
                                   float* __restrict__ xB,
                                   double* __restrict__ psum, double* __restrict__ psq) {
    if (blockIdx.y == 0) gcn_bn_body(hA, idxA, embA, tA, xA, psum, psq, blockIdx.x);
    else                 gcn_bn_body(hB, idxB, embB, tB, xB, psum + (size_t)NPART * D,
                                     psq + (size_t)NPART * D, blockIdx.x);
}

// ---------------- BN finalize over NPART partials (deterministic) ----------------
__device__ __forceinline__ void bn_final_body(const double* __restrict__ psum,
                                              const double* __restrict__ psq,
                                              const float* __restrict__ g,
                                              const float* __restrict__ beta,
                                              float* __restrict__ ss_out) {
    __shared__ double shs[4][D], shq2[4][D];
    int tid = threadIdx.x;
    int c = tid & 63, part = tid >> 6;
    double s = 0.0, qv = 0.0;
    for (int b2 = part; b2 < NPART; b2 += 4) { s += psum[b2 * D + c]; qv += psq[b2 * D + c]; }
    shs[part][c] = s; shq2[part][c] = qv;
    __syncthreads();
    if (part == 0) {
        double S = (shs[0][c] + shs[1][c]) + (shs[2][c] + shs[3][c]);
        double Q = (shq2[0][c] + shq2[1][c]) + (shq2[2][c] + shq2[3][c]);
        const double n = (double)NROWS;
        double mu = S / n;
        double var = Q / n - mu * mu;
        double inv = 1.0 / sqrt(var + 1e-5);
        double sc = (double)g[c] * inv;
        ss_out[c] = (float)sc;
        ss_out[D + c] = (float)((double)beta[c] - mu * sc);
    }
}

__global__ void bn_final_kernel(const double* __restrict__ psum, const double* __restrict__ psq,
                                const float* __restrict__ g, const float* __restrict__ beta,
                                float* __restrict__ ss_out) {
    bn_final_body(psum, psq, g, beta, ss_out);
}

__global__ void bn_final_dual_kernel(const double* __restrict__ psum, const double* __restrict__ psq,
                                     const float* __restrict__ gP, const float* __restrict__ beP,
                                     const float* __restrict__ gN, const float* __restrict__ beN,
                                     float* __restrict__ ssP, float* __restrict__ ssN) {
    if (blockIdx.x == 0) bn_final_body(psum, psq, gP, beP, ssP);
    else                 bn_final_body(psum + (size_t)NPART * D, psq + (size_t)NPART * D, gN, beN, ssN);
}

// ---------------- fused mid: BN-apply + O=v@W_out + head GEMMs, O stays in LDS ----------------
__global__ void mid_fused_kernel(const float* __restrict__ t, const float* __restrict__ ss,
                                 const float* __restrict__ Wo, const float* __restrict__ bo,
                                 const float* __restrict__ Wp, const float* __restrict__ bp,
                                 const float* __restrict__ Wn, const float* __restrict__ bn_,
                                 float* __restrict__ outP, float* __restrict__ outN) {
    __shared__ float Wos[D * D];
    __shared__ float Wps[16 * D];
    __shared__ float Wns[48 * D];
    __shared__ float vs[8][D];
    __shared__ float os[8][D];
    int tid = threadIdx.x;
    for (int e = tid; e < D * D / 4; e += 256) ((float4*)Wos)[e] = ((const float4*)Wo)[e];
    for (int e = tid; e < 16 * D / 4; e += 256) ((float4*)Wps)[e] = ((const float4*)Wp)[e];
    for (int e = tid; e < 48 * D / 4; e += 256) ((float4*)Wns)[e] = ((const float4*)Wn)[e];
    int base = blockIdx.x * 8;
    for (int e = tid; e < 8 * D; e += 256) {
        int r = e >> 6, c = e & 63;
        float x = t[(size_t)(base + r) * D + c];
        vs[r][c] = fmaxf(fmaf(x, ss[c], ss[D + c]), 0.f);
    }
    __syncthreads();
    int lr = tid >> 6, c = tid & 63;
    #pragma unroll
    for (int rep = 0; rep < 2; ++rep) {
        int r = lr * 2 + rep;
        float acc = bo[c];
        #pragma unroll
        for (int k = 0; k < D; ++k) acc = fmaf(vs[r][k], Wos[k * D + c], acc);
        os[r][c] = acc;
    }
    __syncthreads();
    #pragma unroll
    for (int rep = 0; rep < 2; ++rep) {
        int r = lr * 2 + rep;
        float ap = bp[c];
        #pragma unroll
        for (int k = 0; k < 16; ++k) ap = fmaf(os[r][k], Wps[k * D + c], ap);
        float an = bn_[c];
        #pragma unroll
        for (int k = 0; k < 48; ++k) an = fmaf(os[r][16 + k], Wns[k * D + c], an);
        outP[(size_t)(base + r) * D + c] = ap;
        outN[(size_t)(base + r) * D + c] = an;
    }
}

// ---------------- fused heads: float4, 16 rows/block, sub-wave-16 reduction ----------------
__global__ void heads_kernel(const float* __restrict__ tP, const float* __restrict__ ssP,
                             const float* __restrict__ Wp, const float* __restrict__ bp,
                             float* __restrict__ outP,
                             const float* __restrict__ tN, const float* __restrict__ ssN,
                             const float* __restrict__ Wn, const float* __restrict__ bn_,
                             float* __restrict__ outN) {
    int tid = threadIdx.x;
    int rr = tid >> 4, q = tid & 15;
    int row = blockIdx.x * 16 + rr;
    if (blockIdx.y == 0) {
        float4 x4 = *(const float4*)(tP + (size_t)row * D + q * 4);
        float4 sc = *(const float4*)(ssP + q * 4);
        float4 of = *(const float4*)(ssP + D + q * 4);
        float b0 = fmaxf(fmaf(x4.x, sc.x, of.x), 0.f);
        float b1 = fmaxf(fmaf(x4.y, sc.y, of.y), 0.f);
        float b2 = fmaxf(fmaf(x4.z, sc.z, of.z), 0.f);
        float b3 = fmaxf(fmaf(x4.w, sc.w, of.w), 0.f);
        float4 w4 = *(const float4*)(Wp + q * 4);
        float p = b0 * w4.x + b1 * w4.y + b2 * w4.z + b3 * w4.w;
        p += __shfl_down(p, 8, 16);
        p += __shfl_down(p, 4, 16);
        p += __shfl_down(p, 2, 16);
        p += __shfl_down(p, 1, 16);
        if (q == 0) outP[row] = p + bp[0];
    } else {
        float4 x4 = *(const float4*)(tN + (size_t)row * D + q * 4);
        float4 sc = *(const float4*)(ssN + q * 4);
        float4 of = *(const float4*)(ssN + D + q * 4);
        float b0 = fmaxf(fmaf(x4.x, sc.x, of.x), 0.f);
        float b1 = fmaxf(fmaf(x4.y, sc.y, of.y), 0.f);
        float b2 = fmaxf(fmaf(x4.z, sc.z, of.z), 0.f);
        float b3 = fmaxf(fmaf(x4.w, sc.w, of.w), 0.f);
        const float4* wn4 = (const float4*)(Wn + q * 12);   // rows 4q..4q+3 of [64][3]
        float4 wa = wn4[0], wb = wn4[1], wc = wn4[2];
        float p0 = b0 * wa.x + b1 * wa.w + b2 * wb.z + b3 * wc.y;
        float p1 = b0 * wa.y + b1 * wb.x + b2 * wb.w + b3 * wc.z;
        float p2 = b0 * wa.z + b1 * wb.y + b2 * wc.x + b3 * wc.w;
        p0 += __shfl_down(p0, 8, 16);  p0 += __shfl_down(p0, 4, 16);
        p0 += __shfl_down(p0, 2, 16);  p0 += __shfl_down(p0, 1, 16);
        p1 += __shfl_down(p1, 8, 16);  p1 += __shfl_down(p1, 4, 16);
        p1 += __shfl_down(p1, 2, 16);  p1 += __shfl_down(p1, 1, 16);
        p2 += __shfl_down(p2, 8, 16);  p2 += __shfl_down(p2, 4, 16);
        p2 += __shfl_down(p2, 2, 16);  p2 += __shfl_down(p2, 1, 16);
        if (q == 0) {
            outN[(size_t)row * 3 + 0] = p0 + bn_[0];
            outN[(size_t)row * 3 + 1] = p1 + bn_[1];
            outN[(size_t)row * 3 + 2] = p2 + bn_[2];
        }
    }
}

extern "C" void kernel_launch(void* const* d_in, const int* in_sizes, int n_in,
                              void* d_out, int out_size, void* d_ws, size_t ws_size,
                              hipStream_t stream) {
    const float* data    = (const float*)d_in[0];
    const float* mul_emb = (const float*)d_in[4];
    const float* phy_emb = (const float*)d_in[5];
    const float* net_emb = (const float*)d_in[6];
    const float* W_share = (const float*)d_in[7];
    const float* b_share = (const float*)d_in[8];
    const float* W_phy   = (const float*)d_in[9];
    const float* b_phy   = (const float*)d_in[10];
    const float* W_net   = (const float*)d_in[11];
    const float* b_net   = (const float*)d_in[12];
    const float* g_mul   = (const float*)d_in[13];
    const float* be_mul  = (const float*)d_in[14];
    const float* g_phy   = (const float*)d_in[15];
    const float* be_phy  = (const float*)d_in[16];
    const float* g_net   = (const float*)d_in[17];
    const float* be_net  = (const float*)d_in[18];
    const float* W_out   = (const float*)d_in[19];
    const float* b_out   = (const float*)d_in[20];
    const float* W_pout  = (const float*)d_in[21];
    const float* b_pout  = (const float*)d_in[22];
    const float* W_nout  = (const float*)d_in[23];
    const float* b_nout  = (const float*)d_in[24];

    float* outf = (float*)d_out;
    float* out_phy  = outf;            // 32000
    float* out_net  = outf + 32000;    // 96000
    float* out_idx  = outf + 128000;   // 20000 (idx_mul as floats)
    float* out_xnet = outf + 148000;   // 2048000
    float* out_xphy = outf + 2196000;  // 2048000

    char* ws = (char*)d_ws;
    size_t off = 0;
    auto alloc = [&](size_t bytes) -> void* {
        void* p = (void*)(ws + off);
        off += bytes;
        off = (off + 255) & ~(size_t)255;
        return p;
    };
    int* idxM = (int*)alloc(20000 * 4);
    int* idxP = (int*)alloc(20000 * 4);
    int* idxN = (int*)alloc(20000 * 4);
    double* inv_nrm = (double*)alloc(3000 * 8);
    double* psum = (double*)alloc(2 * (size_t)NPART * D * 8);   // 2 banks
    double* psq  = (double*)alloc(2 * (size_t)NPART * D * 8);
    float* ssM = (float*)alloc(128 * 4);
    float* ssP = (float*)alloc(128 * 4);
    float* ssN = (float*)alloc(128 * 4);
    float* A  = (float*)alloc((size_t)NROWS * D * 4);  // h_share -> h_phy
    float* Bb = (float*)alloc((size_t)NROWS * D * 4);  // t_mul   -> h_net
    float* C  = (float*)alloc((size_t)NROWS * D * 4);  // t_phy
    float* Dd = (float*)alloc((size_t)NROWS * D * 4);  // t_net

    // 1. norms, then fused topk (3 graphs) + rowgemm60 (independent work overlap)
    norms_kernel<<<dim3(4, 3), 256, 0, stream>>>(mul_emb, phy_emb, net_emb, inv_nrm);
    topk_gemm_kernel<<<7000, 256, 0, stream>>>(mul_emb, phy_emb, net_emb, inv_nrm,
                                               idxM, idxP, idxN, out_idx,
                                               data, W_share, b_share, A);

    // 2. mul path (gcn + inline BN partials)
    gcn_bn_kernel<<<NPART, 256, 0, stream>>>(A, idxM, mul_emb, Bb, (float*)nullptr, psum, psq);
    bn_final_kernel<<<1, 256, 0, stream>>>(psum, psq, g_mul, be_mul, ssM);
    mid_fused_kernel<<<4000, 256, 0, stream>>>(Bb, ssM, W_out, b_out,
                                               W_phy, b_phy, W_net, b_net, A, Bb);

    // 3. phy / net heads
    gcn_bn_dual_kernel<<<dim3(NPART, 2), 256, 0, stream>>>(A, idxP, phy_emb, C, out_xphy,
                                                           Bb, idxN, net_emb, Dd, out_xnet,
                                                           psum, psq);
    bn_final_dual_kernel<<<2, 256, 0, stream>>>(psum, psq, g_phy, be_phy, g_net, be_net, ssP, ssN);
    heads_kernel<<<dim3(2000, 2), 256, 0, stream>>>(C, ssP, W_pout, b_pout, out_phy,
                                                    Dd, ssN, W_nout, b_nout, out_net);
}

// Round 13
// 173.740 us; speedup vs baseline: 2.6876x; 2.6876x over previous
//
#include <hip/hip_runtime.h>

#define NNODE 1000
#define D 64
#define K_TOP 20
#define NROWS 32000   // B*N = 32*1000
#define GCN_ROWS 16
#define NPART (NROWS / GCN_ROWS)   // 2000 BN partials
#define NRED 25                    // stage-1 reduction blocks (2000 = 25*80)
typedef unsigned long long ull;

// ---------------- inverse norms (f64) ----------------
__global__ void norms_kernel(const float* __restrict__ e0, const float* __restrict__ e1,
                             const float* __restrict__ e2, double* __restrict__ inv_nrm) {
    int g = blockIdx.y;
    const float* e = (g == 0) ? e0 : ((g == 1) ? e1 : e2);
    int j = blockIdx.x * 256 + threadIdx.x;
    if (j < NNODE) {
        double s = 0.0;
        #pragma unroll
        for (int k = 0; k < D; ++k) { double v = (double)e[j * D + k]; s += v * v; }
        inv_nrm[g * NNODE + j] = 1.0 / sqrt(s);
    }
}

__device__ __forceinline__ ull packkey(double cosv, int j) {
    ull b = (ull)__double_as_longlong(cosv);
    ull k = (b >> 63) ? ~b : (b | 0x8000000000000000ULL);
    return (k & ~1023ULL) | (ull)(1023 - j);
}

__device__ __forceinline__ int cnt20(const ull* pl, ull v) {
    const ulonglong2* p2 = (const ulonglong2*)pl;
    int cnt = 0;
    #pragma unroll
    for (int m = 0; m < 10; ++m) {
        ulonglong2 ab = p2[m];
        cnt += (ab.x > v) ? 1 : 0;
        cnt += (ab.y > v) ? 1 : 0;
    }
    return cnt;
}

// ---------------- fused: topk (blocks 0..2999, R11-verified body) + rowgemm60 (blocks 3000..6999) ----
__global__ void __launch_bounds__(256, 2)
topk_gemm_kernel(const float* __restrict__ e0, const float* __restrict__ e1,
                 const float* __restrict__ e2, const double* __restrict__ inv_nrm,
                 int* __restrict__ idxM, int* __restrict__ idxP,
                 int* __restrict__ idxN, float* __restrict__ idxf_out,
                 const float* __restrict__ X, const float* __restrict__ W,
                 const float* __restrict__ bias, float* __restrict__ A) {
    __shared__ __align__(16) char smem[17280];
    int blk = blockIdx.x;
    int tid = threadIdx.x;

    if (blk < 3000) {
        float* srow = (float*)smem;
        ull* skey = (ull*)(smem + 256);
        ull* sw16 = (ull*)(smem + 8448);
        ull* m8   = (ull*)(smem + 11008);
        ull* m4   = (ull*)(smem + 12288);
        ull* m2   = (ull*)(smem + 12928);

        int g = blk / 1000;
        int i = blk - g * 1000;
        const float* emb = (g == 0) ? e0 : ((g == 1) ? e1 : e2);
        int* idx_out = (g == 0) ? idxM : ((g == 1) ? idxP : idxN);
        const double* inv = inv_nrm + g * NNODE;

        int w = tid >> 6, l = tid & 63;
        int rowq = tid >> 2;
        int s = tid & 3;

        if (tid < D) srow[tid] = emb[i * D + tid];
        __syncthreads();

        double inv_i = inv[i];
        const float4* sr4 = (const float4*)srow + s * 4;

        #pragma unroll 2
        for (int p = 0; p < 16; ++p) {
            int j = p * 64 + rowq;
            int jc = (j < NNODE) ? j : 0;
            const float4* ej = (const float4*)(emb + (size_t)jc * D) + s * 4;
            double acc = 0.0;
            #pragma unroll
            for (int q = 0; q < 4; ++q) {
                float4 v = ej[q];
                float4 r = sr4[q];
                acc = fma((double)v.x, (double)r.x, acc);
                acc = fma((double)v.y, (double)r.y, acc);
                acc = fma((double)v.z, (double)r.z, acc);
                acc = fma((double)v.w, (double)r.w, acc);
            }
            acc += __shfl_xor(acc, 1, 64);
            acc += __shfl_xor(acc, 2, 64);
            if (s == 0) {
                double cosv = acc * inv_i * inv[jc];
                skey[j] = (j < NNODE) ? packkey(cosv, j) : 0ULL;
            }
        }
        __syncthreads();

        {
            const ulonglong2* base = (const ulonglong2*)(skey + (w << 8));
            ull k0 = skey[(w << 8) + l];
            ull k1 = skey[(w << 8) + 64 + l];
            ull k2 = skey[(w << 8) + 128 + l];
            ull k3 = skey[(w << 8) + 192 + l];
            int n0 = 0, n1 = 0, n2 = 0, n3 = 0;
            #pragma unroll 8
            for (int m = 0; m < 32; ++m) {
                ulonglong2 a0 = base[m];
                ulonglong2 a1 = base[32 + m];
                ulonglong2 a2 = base[64 + m];
                ulonglong2 a3 = base[96 + m];
                n0 += (a0.x > k0) ? 1 : 0;  n0 += (a0.y > k0) ? 1 : 0;
                n1 += (a1.x > k1) ? 1 : 0;  n1 += (a1.y > k1) ? 1 : 0;
                n2 += (a2.x > k2) ? 1 : 0;  n2 += (a2.y > k2) ? 1 : 0;
                n3 += (a3.x > k3) ? 1 : 0;  n3 += (a3.y > k3) ? 1 : 0;
            }
            if (n0 < K_TOP) sw16[((w << 2) + 0) * K_TOP + n0] = k0;
            if (n1 < K_TOP) sw16[((w << 2) + 1) * K_TOP + n1] = k1;
            if (n2 < K_TOP) sw16[((w << 2) + 2) * K_TOP + n2] = k2;
            if (n3 < K_TOP) sw16[((w << 2) + 3) * K_TOP + n3] = k3;
        }
        __syncthreads();

        {
            int e = tid;
            int lw = e / K_TOP, r = e % K_TOP;
            ull v = sw16[e];
            int rank = r + cnt20(sw16 + (lw ^ 1) * K_TOP, v);
            if (rank < K_TOP) m8[(lw >> 1) * K_TOP + rank] = v;
            if (tid < 64) {
                int e2 = 256 + tid;
                int lw2 = e2 / K_TOP, r2 = e2 % K_TOP;
                ull v2 = sw16[e2];
                int rank2 = r2 + cnt20(sw16 + (lw2 ^ 1) * K_TOP, v2);
                if (rank2 < K_TOP) m8[(lw2 >> 1) * K_TOP + rank2] = v2;
            }
        }
        __syncthreads();
        if (tid < 160) {
            int lw = tid / K_TOP, r = tid % K_TOP;
            ull v = m8[tid];
            int rank = r + cnt20(m8 + (lw ^ 1) * K_TOP, v);
            if (rank < K_TOP) m4[(lw >> 1) * K_TOP + rank] = v;
        }
        __syncthreads();
        if (tid < 80) {
            int lw = tid / K_TOP, r = tid % K_TOP;
            ull v = m4[tid];
            int rank = r + cnt20(m4 + (lw ^ 1) * K_TOP, v);
            if (rank < K_TOP) m2[(lw >> 1) * K_TOP + rank] = v;
        }
        __syncthreads();
        if (tid < 40) {
            int lw = tid / K_TOP, r = tid % K_TOP;
            ull v = m2[tid];
            int rank = r + cnt20(m2 + (lw ^ 1) * K_TOP, v);
            if (rank < K_TOP) {
                int id = 1023 - (int)(v & 1023ULL);
                idx_out[i * K_TOP + rank] = id;
                if (g == 0) idxf_out[i * K_TOP + rank] = (float)id;
            }
        }
    } else {
        const int K = 60;
        float* Ws = (float*)smem;
        float* xs = (float*)(smem + 15360);
        int rb = blk - 3000;
        for (int e = tid; e < K * D; e += 256) Ws[e] = W[e];
        int base_row = rb * 8;
        for (int e = tid; e < 8 * K; e += 256) {
            int r = e / K, k = e % K;
            xs[r * K + k] = X[(size_t)(base_row + r) * K + k];
        }
        __syncthreads();
        int lr = tid >> 6, c = tid & 63;
        #pragma unroll
        for (int rep = 0; rep < 2; ++rep) {
            int r = lr * 2 + rep;
            float acc = bias[c];
            #pragma unroll
            for (int k = 0; k < K; ++k) acc = fmaf(xs[r * K + k], Ws[k * D + c], acc);
            A[(size_t)(base_row + r) * D + c] = acc;
        }
    }
}

// ---------------- GCN gather-mean-relu (float4) + inline BN partial sums ----------------
__device__ __forceinline__ void gcn_bn_body(const float* __restrict__ h, const int* __restrict__ idx,
                                            const float* __restrict__ emb, float* __restrict__ t_out,
                                            float* __restrict__ x_out,
                                            double* __restrict__ psum, double* __restrict__ psq,
                                            int blk) {
    __shared__ int nbrs[GCN_ROWS][K_TOP];
    __shared__ double4 shs[4][16], shq[4][16];
    int tid = threadIdx.x;
    int rr = tid >> 4, q = tid & 15;
    int base_row = blk * GCN_ROWS;
    for (int e = tid; e < GCN_ROWS * K_TOP; e += 256) {
        int r2 = e / K_TOP, tt = e % K_TOP;
        int node = (base_row + r2) % NNODE;
        nbrs[r2][tt] = idx[node * K_TOP + tt];
    }
    __syncthreads();
    int row = base_row + rr;
    int b = row / NNODE, i = row - b * NNODE;
    const float* hb = h + (size_t)b * NNODE * D;
    float4 s4 = make_float4(0.f, 0.f, 0.f, 0.f);
    #pragma unroll
    for (int t = 0; t < K_TOP; ++t) {
        float4 v = *(const float4*)(hb + (size_t)nbrs[rr][t] * D + q * 4);
        s4.x += v.x; s4.y += v.y; s4.z += v.z; s4.w += v.w;
    }
    const float inv20 = 1.0f / 20.0f;
    float4 y4;
    y4.x = fmaxf(s4.x * inv20, 0.f);
    y4.y = fmaxf(s4.y * inv20, 0.f);
    y4.z = fmaxf(s4.z * inv20, 0.f);
    y4.w = fmaxf(s4.w * inv20, 0.f);
    if (x_out) *(float4*)(x_out + (size_t)row * D + q * 4) = y4;
    float4 e4 = *(const float4*)(emb + (size_t)i * D + q * 4);
    float4 t4 = make_float4(y4.x * e4.x, y4.y * e4.y, y4.z * e4.z, y4.w * e4.w);
    *(float4*)(t_out + (size_t)row * D + q * 4) = t4;

    double s0 = t4.x, s1 = t4.y, s2 = t4.z, s3 = t4.w;
    double q0 = s0 * s0, q1 = s1 * s1, q2 = s2 * s2, q3 = s3 * s3;
    s0 += __shfl_xor(s0, 16, 64);  s0 += __shfl_xor(s0, 32, 64);
    s1 += __shfl_xor(s1, 16, 64);  s1 += __shfl_xor(s1, 32, 64);
    s2 += __shfl_xor(s2, 16, 64);  s2 += __shfl_xor(s2, 32, 64);
    s3 += __shfl_xor(s3, 16, 64);  s3 += __shfl_xor(s3, 32, 64);
    q0 += __shfl_xor(q0, 16, 64);  q0 += __shfl_xor(q0, 32, 64);
    q1 += __shfl_xor(q1, 16, 64);  q1 += __shfl_xor(q1, 32, 64);
    q2 += __shfl_xor(q2, 16, 64);  q2 += __shfl_xor(q2, 32, 64);
    q3 += __shfl_xor(q3, 16, 64);  q3 += __shfl_xor(q3, 32, 64);
    int wv = tid >> 6;
    if (((tid >> 4) & 3) == 0) {
        shs[wv][q] = make_double4(s0, s1, s2, s3);
        shq[wv][q] = make_double4(q0, q1, q2, q3);
    }
    __syncthreads();
    if (tid < 16) {
        double a0 = shs[0][tid].x + shs[1][tid].x + shs[2][tid].x + shs[3][tid].x;
        double a1 = shs[0][tid].y + shs[1][tid].y + shs[2][tid].y + shs[3][tid].y;
        double a2 = shs[0][tid].z + shs[1][tid].z + shs[2][tid].z + shs[3][tid].z;
        double a3 = shs[0][tid].w + shs[1][tid].w + shs[2][tid].w + shs[3][tid].w;
        psum[(size_t)blk * D + tid * 4 + 0] = a0;
        psum[(size_t)blk * D + tid * 4 + 1] = a1;
        psum[(size_t)blk * D + tid * 4 + 2] = a2;
        psum[(size_t)blk * D + tid * 4 + 3] = a3;
        double b0 = shq[0][tid].x + shq[1][tid].x + shq[2][tid].x + shq[3][tid].x;
        double b1 = shq[0][tid].y + shq[1][tid].y + shq[2][tid].y + shq[3][tid].y;
        double b2 = shq[0][tid].z + shq[1][tid].z + shq[2][tid].z + shq[3][tid].z;
        double b3 = shq[0][tid].w + shq[1][tid].w + shq[2][tid].w + shq[3][tid].w;
        psq[(size_t)blk * D + tid * 4 + 0] = b0;
        psq[(size_t)blk * D + tid * 4 + 1] = b1;
        psq[(size_t)blk * D + tid * 4 + 2] = b2;
        psq[(size_t)blk * D + tid * 4 + 3] = b3;
    }
}

__global__ void gcn_bn_kernel(const float* __restrict__ h, const int* __restrict__ idx,
                              const float* __restrict__ emb, float* __restrict__ t_out,
                              float* __restrict__ x_out,
                              double* __restrict__ psum, double* __restrict__ psq) {
    gcn_bn_body(h, idx, emb, t_out, x_out, psum, psq, blockIdx.x);
}

__global__ void gcn_bn_dual_kernel(const float* __restrict__ hA, const int* __restrict__ idxA,
                                   const float* __restrict__ embA, float* __restrict__ tA,
                                   float* __restrict__ xA,
                                   const float* __restrict__ hB, const int* __restrict__ idxB,
                                   const float* __restrict__ embB, float* __restrict__ tB,
                                   float* __restrict__ xB,
                                   double* __restrict__ psum, double* __restrict__ psq) {
    if (blockIdx.y == 0) gcn_bn_body(hA, idxA, embA, tA, xA, psum, psq, blockIdx.x);
    else                 gcn_bn_body(hB, idxB, embB, tB, xB, psum + (size_t)NPART * D,
                                     psq + (size_t)NPART * D, blockIdx.x);
}

// ---------------- BN reduce stage 1: 2000 partials -> 25 per bank (parallel, deterministic) ----
__device__ __forceinline__ void bn_reduce_body(const double* __restrict__ psum,
                                               const double* __restrict__ psq,
                                               double* __restrict__ rsum,
                                               double* __restrict__ rsq, int blk) {
    __shared__ double shs[4][D], shq2[4][D];
    int tid = threadIdx.x;
    int c = tid & 63, grp = tid >> 6;
    int base = blk * 80;
    double s = 0.0, qv = 0.0;
    #pragma unroll 4
    for (int p = grp; p < 80; p += 4) {
        s += psum[(size_t)(base + p) * D + c];
        qv += psq[(size_t)(base + p) * D + c];
    }
    shs[grp][c] = s; shq2[grp][c] = qv;
    __syncthreads();
    if (grp == 0) {
        rsum[(size_t)blk * D + c] = (shs[0][c] + shs[1][c]) + (shs[2][c] + shs[3][c]);
        rsq[(size_t)blk * D + c]  = (shq2[0][c] + shq2[1][c]) + (shq2[2][c] + shq2[3][c]);
    }
}

__global__ void bn_reduce_kernel(const double* __restrict__ psum, const double* __restrict__ psq,
                                 double* __restrict__ rsum, double* __restrict__ rsq) {
    size_t boff = (size_t)blockIdx.y * NPART * D;
    size_t roff = (size_t)blockIdx.y * NRED * D;
    bn_reduce_body(psum + boff, psq + boff, rsum + roff, rsq + roff, blockIdx.x);
}

// ---------------- BN finalize over NRED partials (tiny, deterministic) ----------------
__device__ __forceinline__ void bn_final_body(const double* __restrict__ rsum,
                                              const double* __restrict__ rsq,
                                              const float* __restrict__ g,
                                              const float* __restrict__ beta,
                                              float* __restrict__ ss_out) {
    __shared__ double shs[4][D], shq2[4][D];
    int tid = threadIdx.x;
    int c = tid & 63, grp = tid >> 6;
    double s = 0.0, qv = 0.0;
    for (int p = grp; p < NRED; p += 4) { s += rsum[(size_t)p * D + c]; qv += rsq[(size_t)p * D + c]; }
    shs[grp][c] = s; shq2[grp][c] = qv;
    __syncthreads();
    if (grp == 0) {
        double S = (shs[0][c] + shs[1][c]) + (shs[2][c] + shs[3][c]);
        double Q = (shq2[0][c] + shq2[1][c]) + (shq2[2][c] + shq2[3][c]);
        const double n = (double)NROWS;
        double mu = S / n;
        double var = Q / n - mu * mu;
        double inv = 1.0 / sqrt(var + 1e-5);
        double sc = (double)g[c] * inv;
        ss_out[c] = (float)sc;
        ss_out[D + c] = (float)((double)beta[c] - mu * sc);
    }
}

__global__ void bn_final_kernel(const double* __restrict__ rsum, const double* __restrict__ rsq,
                                const float* __restrict__ g, const float* __restrict__ beta,
                                float* __restrict__ ss_out) {
    bn_final_body(rsum, rsq, g, beta, ss_out);
}

__global__ void bn_final_dual_kernel(const double* __restrict__ rsum, const double* __restrict__ rsq,
                                     const float* __restrict__ gP, const float* __restrict__ beP,
                                     const float* __restrict__ gN, const float* __restrict__ beN,
                                     float* __restrict__ ssP, float* __restrict__ ssN) {
    size_t roff = (size_t)NRED * D;
    if (blockIdx.x == 0) bn_final_body(rsum, rsq, gP, beP, ssP);
    else                 bn_final_body(rsum + roff, rsq + roff, gN, beN, ssN);
}

// ---------------- fused mid: BN-apply + O=v@W_out + head GEMMs, O stays in LDS ----------------
__global__ void mid_fused_kernel(const float* __restrict__ t, const float* __restrict__ ss,
                                 const float* __restrict__ Wo, const float* __restrict__ bo,
                                 const float* __restrict__ Wp, const float* __restrict__ bp,
                                 const float* __restrict__ Wn, const float* __restrict__ bn_,
                                 float* __restrict__ outP, float* __restrict__ outN) {
    __shared__ float Wos[D * D];
    __shared__ float Wps[16 * D];
    __shared__ float Wns[48 * D];
    __shared__ float vs[8][D];
    __shared__ float os[8][D];
    int tid = threadIdx.x;
    for (int e = tid; e < D * D / 4; e += 256) ((float4*)Wos)[e] = ((const float4*)Wo)[e];
    for (int e = tid; e < 16 * D / 4; e += 256) ((float4*)Wps)[e] = ((const float4*)Wp)[e];
    for (int e = tid; e < 48 * D / 4; e += 256) ((float4*)Wns)[e] = ((const float4*)Wn)[e];
    int base = blockIdx.x * 8;
    for (int e = tid; e < 8 * D; e += 256) {
        int r = e >> 6, c = e & 63;
        float x = t[(size_t)(base + r) * D + c];
        vs[r][c] = fmaxf(fmaf(x, ss[c], ss[D + c]), 0.f);
    }
    __syncthreads();
    int lr = tid >> 6, c = tid & 63;
    #pragma unroll
    for (int rep = 0; rep < 2; ++rep) {
        int r = lr * 2 + rep;
        float acc = bo[c];
        #pragma unroll
        for (int k = 0; k < D; ++k) acc = fmaf(vs[r][k], Wos[k * D + c], acc);
        os[r][c] = acc;
    }
    __syncthreads();
    #pragma unroll
    for (int rep = 0; rep < 2; ++rep) {
        int r = lr * 2 + rep;
        float ap = bp[c];
        #pragma unroll
        for (int k = 0; k < 16; ++k) ap = fmaf(os[r][k], Wps[k * D + c], ap);
        float an = bn_[c];
        #pragma unroll
        for (int k = 0; k < 48; ++k) an = fmaf(os[r][16 + k], Wns[k * D + c], an);
        outP[(size_t)(base + r) * D + c] = ap;
        outN[(size_t)(base + r) * D + c] = an;
    }
}

// ---------------- fused heads: float4, 16 rows/block, sub-wave-16 reduction ----------------
__global__ void heads_kernel(const float* __restrict__ tP, const float* __restrict__ ssP,
                             const float* __restrict__ Wp, const float* __restrict__ bp,
                             float* __restrict__ outP,
                             const float* __restrict__ tN, const float* __restrict__ ssN,
                             const float* __restrict__ Wn, const float* __restrict__ bn_,
                             float* __restrict__ outN) {
    int tid = threadIdx.x;
    int rr = tid >> 4, q = tid & 15;
    int row = blockIdx.x * 16 + rr;
    if (blockIdx.y == 0) {
        float4 x4 = *(const float4*)(tP + (size_t)row * D + q * 4);
        float4 sc = *(const float4*)(ssP + q * 4);
        float4 of = *(const float4*)(ssP + D + q * 4);
        float b0 = fmaxf(fmaf(x4.x, sc.x, of.x), 0.f);
        float b1 = fmaxf(fmaf(x4.y, sc.y, of.y), 0.f);
        float b2 = fmaxf(fmaf(x4.z, sc.z, of.z), 0.f);
        float b3 = fmaxf(fmaf(x4.w, sc.w, of.w), 0.f);
        float4 w4 = *(const float4*)(Wp + q * 4);
        float p = b0 * w4.x + b1 * w4.y + b2 * w4.z + b3 * w4.w;
        p += __shfl_down(p, 8, 16);
        p += __shfl_down(p, 4, 16);
        p += __shfl_down(p, 2, 16);
        p += __shfl_down(p, 1, 16);
        if (q == 0) outP[row] = p + bp[0];
    } else {
        float4 x4 = *(const float4*)(tN + (size_t)row * D + q * 4);
        float4 sc = *(const float4*)(ssN + q * 4);
        float4 of = *(const float4*)(ssN + D + q * 4);
        float b0 = fmaxf(fmaf(x4.x, sc.x, of.x), 0.f);
        float b1 = fmaxf(fmaf(x4.y, sc.y, of.y), 0.f);
        float b2 = fmaxf(fmaf(x4.z, sc.z, of.z), 0.f);
        float b3 = fmaxf(fmaf(x4.w, sc.w, of.w), 0.f);
        const float4* wn4 = (const float4*)(Wn + q * 12);
        float4 wa = wn4[0], wb = wn4[1], wc = wn4[2];
        float p0 = b0 * wa.x + b1 * wa.w + b2 * wb.z + b3 * wc.y;
        float p1 = b0 * wa.y + b1 * wb.x + b2 * wb.w + b3 * wc.z;
        float p2 = b0 * wa.z + b1 * wb.y + b2 * wc.x + b3 * wc.w;
        p0 += __shfl_down(p0, 8, 16);  p0 += __shfl_down(p0, 4, 16);
        p0 += __shfl_down(p0, 2, 16);  p0 += __shfl_down(p0, 1, 16);
        p1 += __shfl_down(p1, 8, 16);  p1 += __shfl_down(p1, 4, 16);
        p1 += __shfl_down(p1, 2, 16);  p1 += __shfl_down(p1, 1, 16);
        p2 += __shfl_down(p2, 8, 16);  p2 += __shfl_down(p2, 4, 16);
        p2 += __shfl_down(p2, 2, 16);  p2 += __shfl_down(p2, 1, 16);
        if (q == 0) {
            outN[(size_t)row * 3 + 0] = p0 + bn_[0];
            outN[(size_t)row * 3 + 1] = p1 + bn_[1];
            outN[(size_t)row * 3 + 2] = p2 + bn_[2];
        }
    }
}

extern "C" void kernel_launch(void* const* d_in, const int* in_sizes, int n_in,
                              void* d_out, int out_size, void* d_ws, size_t ws_size,
                              hipStream_t stream) {
    const float* data    = (const float*)d_in[0];
    const float* mul_emb = (const float*)d_in[4];
    const float* phy_emb = (const float*)d_in[5];
    const float* net_emb = (const float*)d_in[6];
    const float* W_share = (const float*)d_in[7];
    const float* b_share = (const float*)d_in[8];
    const float* W_phy   = (const float*)d_in[9];
    const float* b_phy   = (const float*)d_in[10];
    const float* W_net   = (const float*)d_in[11];
    const float* b_net   = (const float*)d_in[12];
    const float* g_mul   = (const float*)d_in[13];
    const float* be_mul  = (const float*)d_in[14];
    const float* g_phy   = (const float*)d_in[15];
    const float* be_phy  = (const float*)d_in[16];
    const float* g_net   = (const float*)d_in[17];
    const float* be_net  = (const float*)d_in[18];
    const float* W_out   = (const float*)d_in[19];
    const float* b_out   = (const float*)d_in[20];
    const float* W_pout  = (const float*)d_in[21];
    const float* b_pout  = (const float*)d_in[22];
    const float* W_nout  = (const float*)d_in[23];
    const float* b_nout  = (const float*)d_in[24];

    float* outf = (float*)d_out;
    float* out_phy  = outf;            // 32000
    float* out_net  = outf + 32000;    // 96000
    float* out_idx  = outf + 128000;   // 20000 (idx_mul as floats)
    float* out_xnet = outf + 148000;   // 2048000
    float* out_xphy = outf + 2196000;  // 2048000

    char* ws = (char*)d_ws;
    size_t off = 0;
    auto alloc = [&](size_t bytes) -> void* {
        void* p = (void*)(ws + off);
        off += bytes;
        off = (off + 255) & ~(size_t)255;
        return p;
    };
    int* idxM = (int*)alloc(20000 * 4);
    int* idxP = (int*)alloc(20000 * 4);
    int* idxN = (int*)alloc(20000 * 4);
    double* inv_nrm = (double*)alloc(3000 * 8);
    double* psum = (double*)alloc(2 * (size_t)NPART * D * 8);   // 2 banks
    double* psq  = (double*)alloc(2 * (size_t)NPART * D * 8);
    double* rsum = (double*)alloc(2 * (size_t)NRED * D * 8);    // stage-1 outputs
    double* rsq  = (double*)alloc(2 * (size_t)NRED * D * 8);
    float* ssM = (float*)alloc(128 * 4);
    float* ssP = (float*)alloc(128 * 4);
    float* ssN = (float*)alloc(128 * 4);
    float* A  = (float*)alloc((size_t)NROWS * D * 4);  // h_share -> h_phy
    float* Bb = (float*)alloc((size_t)NROWS * D * 4);  // t_mul   -> h_net
    float* C  = (float*)alloc((size_t)NROWS * D * 4);  // t_phy
    float* Dd = (float*)alloc((size_t)NROWS * D * 4);  // t_net

    // 1. norms, then fused topk (3 graphs) + rowgemm60
    norms_kernel<<<dim3(4, 3), 256, 0, stream>>>(mul_emb, phy_emb, net_emb, inv_nrm);
    topk_gemm_kernel<<<7000, 256, 0, stream>>>(mul_emb, phy_emb, net_emb, inv_nrm,
                                               idxM, idxP, idxN, out_idx,
                                               data, W_share, b_share, A);

    // 2. mul path (gcn + inline BN partials; two-stage parallel finalize)
    gcn_bn_kernel<<<NPART, 256, 0, stream>>>(A, idxM, mul_emb, Bb, (float*)nullptr, psum, psq);
    bn_reduce_kernel<<<dim3(NRED, 1), 256, 0, stream>>>(psum, psq, rsum, rsq);
    bn_final_kernel<<<1, 256, 0, stream>>>(rsum, rsq, g_mul, be_mul, ssM);
    mid_fused_kernel<<<4000, 256, 0, stream>>>(Bb, ssM, W_out, b_out,
                                               W_phy, b_phy, W_net, b_net, A, Bb);

    // 3. phy / net heads
    gcn_bn_dual_kernel<<<dim3(NPART, 2), 256, 0, stream>>>(A, idxP, phy_emb, C, out_xphy,
                                                           Bb, idxN, net_emb, Dd, out_xnet,
                                                           psum, psq);
    bn_reduce_kernel<<<dim3(NRED, 2), 256, 0, stream>>>(psum, psq, rsum, rsq);
    bn_final_dual_kernel<<<2, 256, 0, stream>>>(rsum, rsq, g_phy, be_phy, g_net, be_net, ssP, ssN);
    heads_kernel<<<dim3(2000, 2), 256, 0, stream>>>(C, ssP, W_pout, b_pout, out_phy,
                                                    Dd, ssN, W_nout, b_nout, out_net);
}

// Round 14
// 165.121 us; speedup vs baseline: 2.8279x; 1.0522x over previous
//
#include <hip/hip_runtime.h>

#define NNODE 1000
#define D 64
#define K_TOP 20
#define NROWS 32000   // B*N = 32*1000
#define GCN_ROWS 8
#define NPART (NROWS / GCN_ROWS)   // 4000 BN partials
#define NRED 25                    // 4000 = 25*160
typedef unsigned long long ull;

// ---------------- inverse norms (f64) ----------------
__global__ void norms_kernel(const float* __restrict__ e0, const float* __restrict__ e1,
                             const float* __restrict__ e2, double* __restrict__ inv_nrm) {
    int g = blockIdx.y;
    const float* e = (g == 0) ? e0 : ((g == 1) ? e1 : e2);
    int j = blockIdx.x * 256 + threadIdx.x;
    if (j < NNODE) {
        double s = 0.0;
        #pragma unroll
        for (int k = 0; k < D; ++k) { double v = (double)e[j * D + k]; s += v * v; }
        inv_nrm[g * NNODE + j] = 1.0 / sqrt(s);
    }
}

__device__ __forceinline__ ull packkey(double cosv, int j) {
    ull b = (ull)__double_as_longlong(cosv);
    ull k = (b >> 63) ? ~b : (b | 0x8000000000000000ULL);
    return (k & ~1023ULL) | (ull)(1023 - j);
}

__device__ __forceinline__ int cnt20(const ull* pl, ull v) {
    const ulonglong2* p2 = (const ulonglong2*)pl;
    int cnt = 0;
    #pragma unroll
    for (int m = 0; m < 10; ++m) {
        ulonglong2 ab = p2[m];
        cnt += (ab.x > v) ? 1 : 0;
        cnt += (ab.y > v) ? 1 : 0;
    }
    return cnt;
}

// ---------------- fused: topk (blocks 0..2999, R11-verified body) + rowgemm60 (blocks 3000..6999) ----
__global__ void __launch_bounds__(256, 2)
topk_gemm_kernel(const float* __restrict__ e0, const float* __restrict__ e1,
                 const float* __restrict__ e2, const double* __restrict__ inv_nrm,
                 int* __restrict__ idxM, int* __restrict__ idxP,
                 int* __restrict__ idxN, float* __restrict__ idxf_out,
                 const float* __restrict__ X, const float* __restrict__ W,
                 const float* __restrict__ bias, float* __restrict__ A) {
    __shared__ __align__(16) char smem[17280];
    int blk = blockIdx.x;
    int tid = threadIdx.x;

    if (blk < 3000) {
        float* srow = (float*)smem;
        ull* skey = (ull*)(smem + 256);
        ull* sw16 = (ull*)(smem + 8448);
        ull* m8   = (ull*)(smem + 11008);
        ull* m4   = (ull*)(smem + 12288);
        ull* m2   = (ull*)(smem + 12928);

        int g = blk / 1000;
        int i = blk - g * 1000;
        const float* emb = (g == 0) ? e0 : ((g == 1) ? e1 : e2);
        int* idx_out = (g == 0) ? idxM : ((g == 1) ? idxP : idxN);
        const double* inv = inv_nrm + g * NNODE;

        int w = tid >> 6, l = tid & 63;
        int rowq = tid >> 2;
        int s = tid & 3;

        if (tid < D) srow[tid] = emb[i * D + tid];
        __syncthreads();

        double inv_i = inv[i];
        const float4* sr4 = (const float4*)srow + s * 4;

        #pragma unroll 2
        for (int p = 0; p < 16; ++p) {
            int j = p * 64 + rowq;
            int jc = (j < NNODE) ? j : 0;
            const float4* ej = (const float4*)(emb + (size_t)jc * D) + s * 4;
            double acc = 0.0;
            #pragma unroll
            for (int q = 0; q < 4; ++q) {
                float4 v = ej[q];
                float4 r = sr4[q];
                acc = fma((double)v.x, (double)r.x, acc);
                acc = fma((double)v.y, (double)r.y, acc);
                acc = fma((double)v.z, (double)r.z, acc);
                acc = fma((double)v.w, (double)r.w, acc);
            }
            acc += __shfl_xor(acc, 1, 64);
            acc += __shfl_xor(acc, 2, 64);
            if (s == 0) {
                double cosv = acc * inv_i * inv[jc];
                skey[j] = (j < NNODE) ? packkey(cosv, j) : 0ULL;
            }
        }
        __syncthreads();

        {
            const ulonglong2* base = (const ulonglong2*)(skey + (w << 8));
            ull k0 = skey[(w << 8) + l];
            ull k1 = skey[(w << 8) + 64 + l];
            ull k2 = skey[(w << 8) + 128 + l];
            ull k3 = skey[(w << 8) + 192 + l];
            int n0 = 0, n1 = 0, n2 = 0, n3 = 0;
            #pragma unroll 8
            for (int m = 0; m < 32; ++m) {
                ulonglong2 a0 = base[m];
                ulonglong2 a1 = base[32 + m];
                ulonglong2 a2 = base[64 + m];
                ulonglong2 a3 = base[96 + m];
                n0 += (a0.x > k0) ? 1 : 0;  n0 += (a0.y > k0) ? 1 : 0;
                n1 += (a1.x > k1) ? 1 : 0;  n1 += (a1.y > k1) ? 1 : 0;
                n2 += (a2.x > k2) ? 1 : 0;  n2 += (a2.y > k2) ? 1 : 0;
                n3 += (a3.x > k3) ? 1 : 0;  n3 += (a3.y > k3) ? 1 : 0;
            }
            if (n0 < K_TOP) sw16[((w << 2) + 0) * K_TOP + n0] = k0;
            if (n1 < K_TOP) sw16[((w << 2) + 1) * K_TOP + n1] = k1;
            if (n2 < K_TOP) sw16[((w << 2) + 2) * K_TOP + n2] = k2;
            if (n3 < K_TOP) sw16[((w << 2) + 3) * K_TOP + n3] = k3;
        }
        __syncthreads();

        {
            int e = tid;
            int lw = e / K_TOP, r = e % K_TOP;
            ull v = sw16[e];
            int rank = r + cnt20(sw16 + (lw ^ 1) * K_TOP, v);
            if (rank < K_TOP) m8[(lw >> 1) * K_TOP + rank] = v;
            if (tid < 64) {
                int e2 = 256 + tid;
                int lw2 = e2 / K_TOP, r2 = e2 % K_TOP;
                ull v2 = sw16[e2];
                int rank2 = r2 + cnt20(sw16 + (lw2 ^ 1) * K_TOP, v2);
                if (rank2 < K_TOP) m8[(lw2 >> 1) * K_TOP + rank2] = v2;
            }
        }
        __syncthreads();
        if (tid < 160) {
            int lw = tid / K_TOP, r = tid % K_TOP;
            ull v = m8[tid];
            int rank = r + cnt20(m8 + (lw ^ 1) * K_TOP, v);
            if (rank < K_TOP) m4[(lw >> 1) * K_TOP + rank] = v;
        }
        __syncthreads();
        if (tid < 80) {
            int lw = tid / K_TOP, r = tid % K_TOP;
            ull v = m4[tid];
            int rank = r + cnt20(m4 + (lw ^ 1) * K_TOP, v);
            if (rank < K_TOP) m2[(lw >> 1) * K_TOP + rank] = v;
        }
        __syncthreads();
        if (tid < 40) {
            int lw = tid / K_TOP, r = tid % K_TOP;
            ull v = m2[tid];
            int rank = r + cnt20(m2 + (lw ^ 1) * K_TOP, v);
            if (rank < K_TOP) {
                int id = 1023 - (int)(v & 1023ULL);
                idx_out[i * K_TOP + rank] = id;
                if (g == 0) idxf_out[i * K_TOP + rank] = (float)id;
            }
        }
    } else {
        const int K = 60;
        float* Ws = (float*)smem;
        float* xs = (float*)(smem + 15360);
        int rb = blk - 3000;
        for (int e = tid; e < K * D; e += 256) Ws[e] = W[e];
        int base_row = rb * 8;
        for (int e = tid; e < 8 * K; e += 256) {
            int r = e / K, k = e % K;
            xs[r * K + k] = X[(size_t)(base_row + r) * K + k];
        }
        __syncthreads();
        int lr = tid >> 6, c = tid & 63;
        #pragma unroll
        for (int rep = 0; rep < 2; ++rep) {
            int r = lr * 2 + rep;
            float acc = bias[c];
            #pragma unroll
            for (int k = 0; k < K; ++k) acc = fmaf(xs[r * K + k], Ws[k * D + c], acc);
            A[(size_t)(base_row + r) * D + c] = acc;
        }
    }
}

// ---------------- GCN gather-mean-relu (float4) + inline BN partial sums ----------------
// 8 rows/block, 128 threads. XCD batch-affinity: b = blk & 31 so b%8 == blk%8 —
// under round-robin blockIdx->XCD each XCD gathers only 4 batches (1 MB of h),
// which is L2-resident. Per-row math identical to R13 (t bit-identical); BN
// partial grouping changed (f64 fixed tree, ~1e-15, invisible at f32).
__device__ __forceinline__ void gcn_bn_body(const float* __restrict__ h, const int* __restrict__ idx,
                                            const float* __restrict__ emb, float* __restrict__ t_out,
                                            float* __restrict__ x_out,
                                            double* __restrict__ psum, double* __restrict__ psq,
                                            int blk) {
    __shared__ int nbrs[GCN_ROWS][K_TOP];
    __shared__ double4 shs[2][16], shq[2][16];
    int tid = threadIdx.x;              // 0..127
    int rr = tid >> 4, q = tid & 15;
    int b = blk & 31;                   // batch (b%8 == blk%8 -> XCD affinity)
    int g = blk >> 5;                   // node group 0..124
    int base_node = g * GCN_ROWS;
    for (int e = tid; e < GCN_ROWS * K_TOP; e += 128) {
        int r2 = e / K_TOP, tt = e % K_TOP;
        nbrs[r2][tt] = idx[(base_node + r2) * K_TOP + tt];
    }
    __syncthreads();
    int i = base_node + rr;
    int row = b * NNODE + i;
    const float* hb = h + (size_t)b * NNODE * D;
    float4 s4 = make_float4(0.f, 0.f, 0.f, 0.f);
    #pragma unroll
    for (int t = 0; t < K_TOP; ++t) {
        float4 v = *(const float4*)(hb + (size_t)nbrs[rr][t] * D + q * 4);
        s4.x += v.x; s4.y += v.y; s4.z += v.z; s4.w += v.w;
    }
    const float inv20 = 1.0f / 20.0f;
    float4 y4;
    y4.x = fmaxf(s4.x * inv20, 0.f);
    y4.y = fmaxf(s4.y * inv20, 0.f);
    y4.z = fmaxf(s4.z * inv20, 0.f);
    y4.w = fmaxf(s4.w * inv20, 0.f);
    if (x_out) *(float4*)(x_out + (size_t)row * D + q * 4) = y4;
    float4 e4 = *(const float4*)(emb + (size_t)i * D + q * 4);
    float4 t4 = make_float4(y4.x * e4.x, y4.y * e4.y, y4.z * e4.z, y4.w * e4.w);
    *(float4*)(t_out + (size_t)row * D + q * 4) = t4;

    // f64 column partials over the block's 8 rows (4 rows per wave via shfl)
    double s0 = t4.x, s1 = t4.y, s2 = t4.z, s3 = t4.w;
    double q0 = s0 * s0, q1 = s1 * s1, q2 = s2 * s2, q3 = s3 * s3;
    s0 += __shfl_xor(s0, 16, 64);  s0 += __shfl_xor(s0, 32, 64);
    s1 += __shfl_xor(s1, 16, 64);  s1 += __shfl_xor(s1, 32, 64);
    s2 += __shfl_xor(s2, 16, 64);  s2 += __shfl_xor(s2, 32, 64);
    s3 += __shfl_xor(s3, 16, 64);  s3 += __shfl_xor(s3, 32, 64);
    q0 += __shfl_xor(q0, 16, 64);  q0 += __shfl_xor(q0, 32, 64);
    q1 += __shfl_xor(q1, 16, 64);  q1 += __shfl_xor(q1, 32, 64);
    q2 += __shfl_xor(q2, 16, 64);  q2 += __shfl_xor(q2, 32, 64);
    q3 += __shfl_xor(q3, 16, 64);  q3 += __shfl_xor(q3, 32, 64);
    int wv = tid >> 6;
    if (((tid >> 4) & 3) == 0) {   // local row 0 of each wave
        shs[wv][q] = make_double4(s0, s1, s2, s3);
        shq[wv][q] = make_double4(q0, q1, q2, q3);
    }
    __syncthreads();
    if (tid < 16) {
        double a0 = shs[0][tid].x + shs[1][tid].x;
        double a1 = shs[0][tid].y + shs[1][tid].y;
        double a2 = shs[0][tid].z + shs[1][tid].z;
        double a3 = shs[0][tid].w + shs[1][tid].w;
        psum[(size_t)blk * D + tid * 4 + 0] = a0;
        psum[(size_t)blk * D + tid * 4 + 1] = a1;
        psum[(size_t)blk * D + tid * 4 + 2] = a2;
        psum[(size_t)blk * D + tid * 4 + 3] = a3;
        double b0 = shq[0][tid].x + shq[1][tid].x;
        double b1 = shq[0][tid].y + shq[1][tid].y;
        double b2 = shq[0][tid].z + shq[1][tid].z;
        double b3 = shq[0][tid].w + shq[1][tid].w;
        psq[(size_t)blk * D + tid * 4 + 0] = b0;
        psq[(size_t)blk * D + tid * 4 + 1] = b1;
        psq[(size_t)blk * D + tid * 4 + 2] = b2;
        psq[(size_t)blk * D + tid * 4 + 3] = b3;
    }
}

__global__ void gcn_bn_kernel(const float* __restrict__ h, const int* __restrict__ idx,
                              const float* __restrict__ emb, float* __restrict__ t_out,
                              float* __restrict__ x_out,
                              double* __restrict__ psum, double* __restrict__ psq) {
    gcn_bn_body(h, idx, emb, t_out, x_out, psum, psq, blockIdx.x);
}

__global__ void gcn_bn_dual_kernel(const float* __restrict__ hA, const int* __restrict__ idxA,
                                   const float* __restrict__ embA, float* __restrict__ tA,
                                   float* __restrict__ xA,
                                   const float* __restrict__ hB, const int* __restrict__ idxB,
                                   const float* __restrict__ embB, float* __restrict__ tB,
                                   float* __restrict__ xB,
                                   double* __restrict__ psum, double* __restrict__ psq) {
    if (blockIdx.y == 0) gcn_bn_body(hA, idxA, embA, tA, xA, psum, psq, blockIdx.x);
    else                 gcn_bn_body(hB, idxB, embB, tB, xB, psum + (size_t)NPART * D,
                                     psq + (size_t)NPART * D, blockIdx.x);
}

// ---------------- BN reduce stage 1: 4000 partials -> 25 per bank (parallel, deterministic) ----
__device__ __forceinline__ void bn_reduce_body(const double* __restrict__ psum,
                                               const double* __restrict__ psq,
                                               double* __restrict__ rsum,
                                               double* __restrict__ rsq, int blk) {
    __shared__ double shs[4][D], shq2[4][D];
    int tid = threadIdx.x;
    int c = tid & 63, grp = tid >> 6;
    int base = blk * 160;
    double s = 0.0, qv = 0.0;
    #pragma unroll 4
    for (int p = grp; p < 160; p += 4) {
        s += psum[(size_t)(base + p) * D + c];
        qv += psq[(size_t)(base + p) * D + c];
    }
    shs[grp][c] = s; shq2[grp][c] = qv;
    __syncthreads();
    if (grp == 0) {
        rsum[(size_t)blk * D + c] = (shs[0][c] + shs[1][c]) + (shs[2][c] + shs[3][c]);
        rsq[(size_t)blk * D + c]  = (shq2[0][c] + shq2[1][c]) + (shq2[2][c] + shq2[3][c]);
    }
}

__global__ void bn_reduce_kernel(const double* __restrict__ psum, const double* __restrict__ psq,
                                 double* __restrict__ rsum, double* __restrict__ rsq) {
    size_t boff = (size_t)blockIdx.y * NPART * D;
    size_t roff = (size_t)blockIdx.y * NRED * D;
    bn_reduce_body(psum + boff, psq + boff, rsum + roff, rsq + roff, blockIdx.x);
}

// ---------------- BN finalize over NRED partials (tiny, deterministic) ----------------
__device__ __forceinline__ void bn_final_body(const double* __restrict__ rsum,
                                              const double* __restrict__ rsq,
                                              const float* __restrict__ g,
                                              const float* __restrict__ beta,
                                              float* __restrict__ ss_out) {
    __shared__ double shs[4][D], shq2[4][D];
    int tid = threadIdx.x;
    int c = tid & 63, grp = tid >> 6;
    double s = 0.0, qv = 0.0;
    for (int p = grp; p < NRED; p += 4) { s += rsum[(size_t)p * D + c]; qv += rsq[(size_t)p * D + c]; }
    shs[grp][c] = s; shq2[grp][c] = qv;
    __syncthreads();
    if (grp == 0) {
        double S = (shs[0][c] + shs[1][c]) + (shs[2][c] + shs[3][c]);
        double Q = (shq2[0][c] + shq2[1][c]) + (shq2[2][c] + shq2[3][c]);
        const double n = (double)NROWS;
        double mu = S / n;
        double var = Q / n - mu * mu;
        double inv = 1.0 / sqrt(var + 1e-5);
        double sc = (double)g[c] * inv;
        ss_out[c] = (float)sc;
        ss_out[D + c] = (float)((double)beta[c] - mu * sc);
    }
}

__global__ void bn_final_kernel(const double* __restrict__ rsum, const double* __restrict__ rsq,
                                const float* __restrict__ g, const float* __restrict__ beta,
                                float* __restrict__ ss_out) {
    bn_final_body(rsum, rsq, g, beta, ss_out);
}

__global__ void bn_final_dual_kernel(const double* __restrict__ rsum, const double* __restrict__ rsq,
                                     const float* __restrict__ gP, const float* __restrict__ beP,
                                     const float* __restrict__ gN, const float* __restrict__ beN,
                                     float* __restrict__ ssP, float* __restrict__ ssN) {
    size_t roff = (size_t)NRED * D;
    if (blockIdx.x == 0) bn_final_body(rsum, rsq, gP, beP, ssP);
    else                 bn_final_body(rsum + roff, rsq + roff, gN, beN, ssN);
}

// ---------------- fused mid: BN-apply + O=v@W_out + head GEMMs, O stays in LDS ----------------
__global__ void mid_fused_kernel(const float* __restrict__ t, const float* __restrict__ ss,
                                 const float* __restrict__ Wo, const float* __restrict__ bo,
                                 const float* __restrict__ Wp, const float* __restrict__ bp,
                                 const float* __restrict__ Wn, const float* __restrict__ bn_,
                                 float* __restrict__ outP, float* __restrict__ outN) {
    __shared__ float Wos[D * D];
    __shared__ float Wps[16 * D];
    __shared__ float Wns[48 * D];
    __shared__ float vs[8][D];
    __shared__ float os[8][D];
    int tid = threadIdx.x;
    for (int e = tid; e < D * D / 4; e += 256) ((float4*)Wos)[e] = ((const float4*)Wo)[e];
    for (int e = tid; e < 16 * D / 4; e += 256) ((float4*)Wps)[e] = ((const float4*)Wp)[e];
    for (int e = tid; e < 48 * D / 4; e += 256) ((float4*)Wns)[e] = ((const float4*)Wn)[e];
    int base = blockIdx.x * 8;
    for (int e = tid; e < 8 * D; e += 256) {
        int r = e >> 6, c = e & 63;
        float x = t[(size_t)(base + r) * D + c];
        vs[r][c] = fmaxf(fmaf(x, ss[c], ss[D + c]), 0.f);
    }
    __syncthreads();
    int lr = tid >> 6, c = tid & 63;
    #pragma unroll
    for (int rep = 0; rep < 2; ++rep) {
        int r = lr * 2 + rep;
        float acc = bo[c];
        #pragma unroll
        for (int k = 0; k < D; ++k) acc = fmaf(vs[r][k], Wos[k * D + c], acc);
        os[r][c] = acc;
    }
    __syncthreads();
    #pragma unroll
    for (int rep = 0; rep < 2; ++rep) {
        int r = lr * 2 + rep;
        float ap = bp[c];
        #pragma unroll
        for (int k = 0; k < 16; ++k) ap = fmaf(os[r][k], Wps[k * D + c], ap);
        float an = bn_[c];
        #pragma unroll
        for (int k = 0; k < 48; ++k) an = fmaf(os[r][16 + k], Wns[k * D + c], an);
        outP[(size_t)(base + r) * D + c] = ap;
        outN[(size_t)(base + r) * D + c] = an;
    }
}

// ---------------- fused heads: float4, 16 rows/block, sub-wave-16 reduction ----------------
__global__ void heads_kernel(const float* __restrict__ tP, const float* __restrict__ ssP,
                             const float* __restrict__ Wp, const float* __restrict__ bp,
                             float* __restrict__ outP,
                             const float* __restrict__ tN, const float* __restrict__ ssN,
                             const float* __restrict__ Wn, const float* __restrict__ bn_,
                             float* __restrict__ outN) {
    int tid = threadIdx.x;
    int rr = tid >> 4, q = tid & 15;
    int row = blockIdx.x * 16 + rr;
    if (blockIdx.y == 0) {
        float4 x4 = *(const float4*)(tP + (size_t)row * D + q * 4);
        float4 sc = *(const float4*)(ssP + q * 4);
        float4 of = *(const float4*)(ssP + D + q * 4);
        float b0 = fmaxf(fmaf(x4.x, sc.x, of.x), 0.f);
        float b1 = fmaxf(fmaf(x4.y, sc.y, of.y), 0.f);
        float b2 = fmaxf(fmaf(x4.z, sc.z, of.z), 0.f);
        float b3 = fmaxf(fmaf(x4.w, sc.w, of.w), 0.f);
        float4 w4 = *(const float4*)(Wp + q * 4);
        float p = b0 * w4.x + b1 * w4.y + b2 * w4.z + b3 * w4.w;
        p += __shfl_down(p, 8, 16);
        p += __shfl_down(p, 4, 16);
        p += __shfl_down(p, 2, 16);
        p += __shfl_down(p, 1, 16);
        if (q == 0) outP[row] = p + bp[0];
    } else {
        float4 x4 = *(const float4*)(tN + (size_t)row * D + q * 4);
        float4 sc = *(const float4*)(ssN + q * 4);
        float4 of = *(const float4*)(ssN + D + q * 4);
        float b0 = fmaxf(fmaf(x4.x, sc.x, of.x), 0.f);
        float b1 = fmaxf(fmaf(x4.y, sc.y, of.y), 0.f);
        float b2 = fmaxf(fmaf(x4.z, sc.z, of.z), 0.f);
        float b3 = fmaxf(fmaf(x4.w, sc.w, of.w), 0.f);
        const float4* wn4 = (const float4*)(Wn + q * 12);
        float4 wa = wn4[0], wb = wn4[1], wc = wn4[2];
        float p0 = b0 * wa.x + b1 * wa.w + b2 * wb.z + b3 * wc.y;
        float p1 = b0 * wa.y + b1 * wb.x + b2 * wb.w + b3 * wc.z;
        float p2 = b0 * wa.z + b1 * wb.y + b2 * wc.x + b3 * wc.w;
        p0 += __shfl_down(p0, 8, 16);  p0 += __shfl_down(p0, 4, 16);
        p0 += __shfl_down(p0, 2, 16);  p0 += __shfl_down(p0, 1, 16);
        p1 += __shfl_down(p1, 8, 16);  p1 += __shfl_down(p1, 4, 16);
        p1 += __shfl_down(p1, 2, 16);  p1 += __shfl_down(p1, 1, 16);
        p2 += __shfl_down(p2, 8, 16);  p2 += __shfl_down(p2, 4, 16);
        p2 += __shfl_down(p2, 2, 16);  p2 += __shfl_down(p2, 1, 16);
        if (q == 0) {
            outN[(size_t)row * 3 + 0] = p0 + bn_[0];
            outN[(size_t)row * 3 + 1] = p1 + bn_[1];
            outN[(size_t)row * 3 + 2] = p2 + bn_[2];
        }
    }
}

extern "C" void kernel_launch(void* const* d_in, const int* in_sizes, int n_in,
                              void* d_out, int out_size, void* d_ws, size_t ws_size,
                              hipStream_t stream) {
    const float* data    = (const float*)d_in[0];
    const float* mul_emb = (const float*)d_in[4];
    const float* phy_emb = (const float*)d_in[5];
    const float* net_emb = (const float*)d_in[6];
    const float* W_share = (const float*)d_in[7];
    const float* b_share = (const float*)d_in[8];
    const float* W_phy   = (const float*)d_in[9];
    const float* b_phy   = (const float*)d_in[10];
    const float* W_net   = (const float*)d_in[11];
    const float* b_net   = (const float*)d_in[12];
    const float* g_mul   = (const float*)d_in[13];
    const float* be_mul  = (const float*)d_in[14];
    const float* g_phy   = (const float*)d_in[15];
    const float* be_phy  = (const float*)d_in[16];
    const float* g_net   = (const float*)d_in[17];
    const float* be_net  = (const float*)d_in[18];
    const float* W_out   = (const float*)d_in[19];
    const float* b_out   = (const float*)d_in[20];
    const float* W_pout  = (const float*)d_in[21];
    const float* b_pout  = (const float*)d_in[22];
    const float* W_nout  = (const float*)d_in[23];
    const float* b_nout  = (const float*)d_in[24];

    float* outf = (float*)d_out;
    float* out_phy  = outf;            // 32000
    float* out_net  = outf + 32000;    // 96000
    float* out_idx  = outf + 128000;   // 20000 (idx_mul as floats)
    float* out_xnet = outf + 148000;   // 2048000
    float* out_xphy = outf + 2196000;  // 2048000

    char* ws = (char*)d_ws;
    size_t off = 0;
    auto alloc = [&](size_t bytes) -> void* {
        void* p = (void*)(ws + off);
        off += bytes;
        off = (off + 255) & ~(size_t)255;
        return p;
    };
    int* idxM = (int*)alloc(20000 * 4);
    int* idxP = (int*)alloc(20000 * 4);
    int* idxN = (int*)alloc(20000 * 4);
    double* inv_nrm = (double*)alloc(3000 * 8);
    double* psum = (double*)alloc(2 * (size_t)NPART * D * 8);   // 2 banks
    double* psq  = (double*)alloc(2 * (size_t)NPART * D * 8);
    double* rsum = (double*)alloc(2 * (size_t)NRED * D * 8);
    double* rsq  = (double*)alloc(2 * (size_t)NRED * D * 8);
    float* ssM = (float*)alloc(128 * 4);
    float* ssP = (float*)alloc(128 * 4);
    float* ssN = (float*)alloc(128 * 4);
    float* A  = (float*)alloc((size_t)NROWS * D * 4);  // h_share -> h_phy
    float* Bb = (float*)alloc((size_t)NROWS * D * 4);  // t_mul   -> h_net
    float* C  = (float*)alloc((size_t)NROWS * D * 4);  // t_phy
    float* Dd = (float*)alloc((size_t)NROWS * D * 4);  // t_net

    // 1. norms, then fused topk (3 graphs) + rowgemm60
    norms_kernel<<<dim3(4, 3), 256, 0, stream>>>(mul_emb, phy_emb, net_emb, inv_nrm);
    topk_gemm_kernel<<<7000, 256, 0, stream>>>(mul_emb, phy_emb, net_emb, inv_nrm,
                                               idxM, idxP, idxN, out_idx,
                                               data, W_share, b_share, A);

    // 2. mul path (gcn + inline BN partials; two-stage parallel finalize)
    gcn_bn_kernel<<<NPART, 128, 0, stream>>>(A, idxM, mul_emb, Bb, (float*)nullptr, psum, psq);
    bn_reduce_kernel<<<dim3(NRED, 1), 256, 0, stream>>>(psum, psq, rsum, rsq);
    bn_final_kernel<<<1, 256, 0, stream>>>(rsum, rsq, g_mul, be_mul, ssM);
    mid_fused_kernel<<<4000, 256, 0, stream>>>(Bb, ssM, W_out, b_out,
                                               W_phy, b_phy, W_net, b_net, A, Bb);

    // 3. phy / net heads
    gcn_bn_dual_kernel<<<dim3(NPART, 2), 128, 0, stream>>>(A, idxP, phy_emb, C, out_xphy,
                                                           Bb, idxN, net_emb, Dd, out_xnet,
                                                           psum, psq);
    bn_reduce_kernel<<<dim3(NRED, 2), 256, 0, stream>>>(psum, psq, rsum, rsq);
    bn_final_dual_kernel<<<2, 256, 0, stream>>>(rsum, rsq, g_phy, be_phy, g_net, be_net, ssP, ssN);
    heads_kernel<<<dim3(2000, 2), 256, 0, stream>>>(C, ssP, W_pout, b_pout, out_phy,
                                                    Dd, ssN, W_nout, b_nout, out_net);
}

// Round 15
// 149.946 us; speedup vs baseline: 3.1141x; 1.1012x over previous
//
#include <hip/hip_runtime.h>

#define NNODE 1000
#define D 64
#define K_TOP 20
#define NROWS 32000   // B*N = 32*1000
#define GCN_ROWS 8
#define NPART (NROWS / GCN_ROWS)   // 4000 BN partials
#define NRED 25                    // 4000 = 25*160
typedef unsigned long long ull;

// ---------------- inverse norms (f64) ----------------
__global__ void norms_kernel(const float* __restrict__ e0, const float* __restrict__ e1,
                             const float* __restrict__ e2, double* __restrict__ inv_nrm) {
    int g = blockIdx.y;
    const float* e = (g == 0) ? e0 : ((g == 1) ? e1 : e2);
    int j = blockIdx.x * 256 + threadIdx.x;
    if (j < NNODE) {
        double s = 0.0;
        #pragma unroll
        for (int k = 0; k < D; ++k) { double v = (double)e[j * D + k]; s += v * v; }
        inv_nrm[g * NNODE + j] = 1.0 / sqrt(s);
    }
}

__device__ __forceinline__ ull packkey(double cosv, int j) {
    ull b = (ull)__double_as_longlong(cosv);
    ull k = (b >> 63) ? ~b : (b | 0x8000000000000000ULL);
    return (k & ~1023ULL) | (ull)(1023 - j);
}

__device__ __forceinline__ int cnt20(const ull* pl, ull v) {
    const ulonglong2* p2 = (const ulonglong2*)pl;
    int cnt = 0;
    #pragma unroll
    for (int m = 0; m < 10; ++m) {
        ulonglong2 ab = p2[m];
        cnt += (ab.x > v) ? 1 : 0;
        cnt += (ab.y > v) ? 1 : 0;
    }
    return cnt;
}

// ---- fused: topk 2-queries/block (blocks 0..1499) + rowgemm60 (blocks 1500..5499) ----
// Candidate row loaded ONCE, dotted vs 2 query rows (halves L2 stream, doubles
// FMA/load). Per-dot FMA order, quad-fold, and key pack byte-identical to the
// verified R11 kernel -> bit-identical indices. Merge scratch m8/m4/m2 shared
// across the 2 queries (uniform-barrier qq loop) keeps LDS at 24.3 KB.
__global__ void __launch_bounds__(256, 2)
topk_gemm_kernel(const float* __restrict__ e0, const float* __restrict__ e1,
                 const float* __restrict__ e2, const double* __restrict__ inv_nrm,
                 int* __restrict__ idxM, int* __restrict__ idxP,
                 int* __restrict__ idxN, float* __restrict__ idxf_out,
                 const float* __restrict__ X, const float* __restrict__ W,
                 const float* __restrict__ bias, float* __restrict__ A) {
    __shared__ __align__(16) char smem[24256];
    int blk = blockIdx.x;
    int tid = threadIdx.x;

    if (blk < 1500) {
        float* srow = (float*)smem;                  // 2*64*4 = 512 B
        ull* skey  = (ull*)(smem + 512);             // 2*1024*8 = 16384
        ull* sw16  = (ull*)(smem + 16896);           // 2*320*8 = 5120
        ull* m8    = (ull*)(smem + 22016);           // 160*8
        ull* m4    = (ull*)(smem + 23296);           // 80*8
        ull* m2    = (ull*)(smem + 23936);           // 40*8

        int g = blk / 500;
        int i0 = (blk - g * 500) * 2;                // queries i0, i0+1
        const float* emb = (g == 0) ? e0 : ((g == 1) ? e1 : e2);
        int* idx_out = (g == 0) ? idxM : ((g == 1) ? idxP : idxN);
        const double* inv = inv_nrm + g * NNODE;

        int w = tid >> 6, l = tid & 63;
        int rowq = tid >> 2;
        int s = tid & 3;

        if (tid < 2 * D) srow[tid] = emb[(i0 + (tid >> 6)) * D + (tid & 63)];
        __syncthreads();

        double inv_i0 = inv[i0];
        double inv_i1 = inv[i0 + 1];
        const float4* sr0 = (const float4*)srow + s * 4;
        const float4* sr1 = (const float4*)(srow + D) + s * 4;

        // dot phase: 16 coalesced passes; candidate loaded once, 2 queries
        #pragma unroll 2
        for (int p = 0; p < 16; ++p) {
            int j = p * 64 + rowq;
            int jc = (j < NNODE) ? j : 0;
            const float4* ej = (const float4*)(emb + (size_t)jc * D) + s * 4;
            double a0 = 0.0, a1 = 0.0;
            #pragma unroll
            for (int q = 0; q < 4; ++q) {
                float4 v = ej[q];
                float4 r0 = sr0[q];
                float4 r1 = sr1[q];
                a0 = fma((double)v.x, (double)r0.x, a0);
                a0 = fma((double)v.y, (double)r0.y, a0);
                a0 = fma((double)v.z, (double)r0.z, a0);
                a0 = fma((double)v.w, (double)r0.w, a0);
                a1 = fma((double)v.x, (double)r1.x, a1);
                a1 = fma((double)v.y, (double)r1.y, a1);
                a1 = fma((double)v.z, (double)r1.z, a1);
                a1 = fma((double)v.w, (double)r1.w, a1);
            }
            a0 += __shfl_xor(a0, 1, 64);  a0 += __shfl_xor(a0, 2, 64);
            a1 += __shfl_xor(a1, 1, 64);  a1 += __shfl_xor(a1, 2, 64);
            if (s == 0) {
                double invj = inv[jc];
                bool ok = (j < NNODE);
                skey[j]        = ok ? packkey(a0 * inv_i0 * invj, j) : 0ULL;
                skey[1024 + j] = ok ? packkey(a1 * inv_i1 * invj, j) : 0ULL;
            }
        }
        __syncthreads();

        // stage 1: per query, rank within 64-key sub-chunks (named scalars)
        for (int qq = 0; qq < 2; ++qq) {
            const ull* sq = skey + qq * 1024;
            ull* swq = sw16 + qq * 320;
            const ulonglong2* base = (const ulonglong2*)(sq + (w << 8));
            ull k0 = sq[(w << 8) + l];
            ull k1 = sq[(w << 8) + 64 + l];
            ull k2 = sq[(w << 8) + 128 + l];
            ull k3 = sq[(w << 8) + 192 + l];
            int n0 = 0, n1 = 0, n2 = 0, n3 = 0;
            #pragma unroll 8
            for (int m = 0; m < 32; ++m) {
                ulonglong2 a0 = base[m];
                ulonglong2 a1 = base[32 + m];
                ulonglong2 a2 = base[64 + m];
                ulonglong2 a3 = base[96 + m];
                n0 += (a0.x > k0) ? 1 : 0;  n0 += (a0.y > k0) ? 1 : 0;
                n1 += (a1.x > k1) ? 1 : 0;  n1 += (a1.y > k1) ? 1 : 0;
                n2 += (a2.x > k2) ? 1 : 0;  n2 += (a2.y > k2) ? 1 : 0;
                n3 += (a3.x > k3) ? 1 : 0;  n3 += (a3.y > k3) ? 1 : 0;
            }
            if (n0 < K_TOP) swq[((w << 2) + 0) * K_TOP + n0] = k0;
            if (n1 < K_TOP) swq[((w << 2) + 1) * K_TOP + n1] = k1;
            if (n2 < K_TOP) swq[((w << 2) + 2) * K_TOP + n2] = k2;
            if (n3 < K_TOP) swq[((w << 2) + 3) * K_TOP + n3] = k3;
        }
        __syncthreads();

        // stage 2: tournament merge per query (m8/m4/m2 reused; uniform barriers)
        for (int qq = 0; qq < 2; ++qq) {
            const ull* sw = sw16 + qq * 320;
            int i = i0 + qq;
            {
                int e = tid;
                int lw = e / K_TOP, r = e % K_TOP;
                ull v = sw[e];
                int rank = r + cnt20(sw + (lw ^ 1) * K_TOP, v);
                if (rank < K_TOP) m8[(lw >> 1) * K_TOP + rank] = v;
                if (tid < 64) {
                    int e2 = 256 + tid;
                    int lw2 = e2 / K_TOP, r2 = e2 % K_TOP;
                    ull v2 = sw[e2];
                    int rank2 = r2 + cnt20(sw + (lw2 ^ 1) * K_TOP, v2);
                    if (rank2 < K_TOP) m8[(lw2 >> 1) * K_TOP + rank2] = v2;
                }
            }
            __syncthreads();
            if (tid < 160) {
                int lw = tid / K_TOP, r = tid % K_TOP;
                ull v = m8[tid];
                int rank = r + cnt20(m8 + (lw ^ 1) * K_TOP, v);
                if (rank < K_TOP) m4[(lw >> 1) * K_TOP + rank] = v;
            }
            __syncthreads();
            if (tid < 80) {
                int lw = tid / K_TOP, r = tid % K_TOP;
                ull v = m4[tid];
                int rank = r + cnt20(m4 + (lw ^ 1) * K_TOP, v);
                if (rank < K_TOP) m2[(lw >> 1) * K_TOP + rank] = v;
            }
            __syncthreads();
            if (tid < 40) {
                int lw = tid / K_TOP, r = tid % K_TOP;
                ull v = m2[tid];
                int rank = r + cnt20(m2 + (lw ^ 1) * K_TOP, v);
                if (rank < K_TOP) {
                    int id = 1023 - (int)(v & 1023ULL);
                    idx_out[i * K_TOP + rank] = id;
                    if (g == 0) idxf_out[i * K_TOP + rank] = (float)id;
                }
            }
            __syncthreads();
        }
    } else {
        const int K = 60;
        float* Ws = (float*)smem;
        float* xs = (float*)(smem + 15360);
        int rb = blk - 1500;
        for (int e = tid; e < K * D; e += 256) Ws[e] = W[e];
        int base_row = rb * 8;
        for (int e = tid; e < 8 * K; e += 256) {
            int r = e / K, k = e % K;
            xs[r * K + k] = X[(size_t)(base_row + r) * K + k];
        }
        __syncthreads();
        int lr = tid >> 6, c = tid & 63;
        #pragma unroll
        for (int rep = 0; rep < 2; ++rep) {
            int r = lr * 2 + rep;
            float acc = bias[c];
            #pragma unroll
            for (int k = 0; k < K; ++k) acc = fmaf(xs[r * K + k], Ws[k * D + c], acc);
            A[(size_t)(base_row + r) * D + c] = acc;
        }
    }
}

// ---------------- GCN gather-mean-relu (float4) + inline BN partial sums ----------------
__device__ __forceinline__ void gcn_bn_body(const float* __restrict__ h, const int* __restrict__ idx,
                                            const float* __restrict__ emb, float* __restrict__ t_out,
                                            float* __restrict__ x_out,
                                            double* __restrict__ psum, double* __restrict__ psq,
                                            int blk) {
    __shared__ int nbrs[GCN_ROWS][K_TOP];
    __shared__ double4 shs[2][16], shq[2][16];
    int tid = threadIdx.x;              // 0..127
    int rr = tid >> 4, q = tid & 15;
    int b = blk & 31;                   // batch (b%8 == blk%8 -> XCD affinity)
    int g = blk >> 5;                   // node group 0..124
    int base_node = g * GCN_ROWS;
    for (int e = tid; e < GCN_ROWS * K_TOP; e += 128) {
        int r2 = e / K_TOP, tt = e % K_TOP;
        nbrs[r2][tt] = idx[(base_node + r2) * K_TOP + tt];
    }
    __syncthreads();
    int i = base_node + rr;
    int row = b * NNODE + i;
    const float* hb = h + (size_t)b * NNODE * D;
    float4 s4 = make_float4(0.f, 0.f, 0.f, 0.f);
    #pragma unroll
    for (int t = 0; t < K_TOP; ++t) {
        float4 v = *(const float4*)(hb + (size_t)nbrs[rr][t] * D + q * 4);
        s4.x += v.x; s4.y += v.y; s4.z += v.z; s4.w += v.w;
    }
    const float inv20 = 1.0f / 20.0f;
    float4 y4;
    y4.x = fmaxf(s4.x * inv20, 0.f);
    y4.y = fmaxf(s4.y * inv20, 0.f);
    y4.z = fmaxf(s4.z * inv20, 0.f);
    y4.w = fmaxf(s4.w * inv20, 0.f);
    if (x_out) *(float4*)(x_out + (size_t)row * D + q * 4) = y4;
    float4 e4 = *(const float4*)(emb + (size_t)i * D + q * 4);
    float4 t4 = make_float4(y4.x * e4.x, y4.y * e4.y, y4.z * e4.z, y4.w * e4.w);
    *(float4*)(t_out + (size_t)row * D + q * 4) = t4;

    double s0 = t4.x, s1 = t4.y, s2 = t4.z, s3 = t4.w;
    double q0 = s0 * s0, q1 = s1 * s1, q2 = s2 * s2, q3 = s3 * s3;
    s0 += __shfl_xor(s0, 16, 64);  s0 += __shfl_xor(s0, 32, 64);
    s1 += __shfl_xor(s1, 16, 64);  s1 += __shfl_xor(s1, 32, 64);
    s2 += __shfl_xor(s2, 16, 64);  s2 += __shfl_xor(s2, 32, 64);
    s3 += __shfl_xor(s3, 16, 64);  s3 += __shfl_xor(s3, 32, 64);
    q0 += __shfl_xor(q0, 16, 64);  q0 += __shfl_xor(q0, 32, 64);
    q1 += __shfl_xor(q1, 16, 64);  q1 += __shfl_xor(q1, 32, 64);
    q2 += __shfl_xor(q2, 16, 64);  q2 += __shfl_xor(q2, 32, 64);
    q3 += __shfl_xor(q3, 16, 64);  q3 += __shfl_xor(q3, 32, 64);
    int wv = tid >> 6;
    if (((tid >> 4) & 3) == 0) {
        shs[wv][q] = make_double4(s0, s1, s2, s3);
        shq[wv][q] = make_double4(q0, q1, q2, q3);
    }
    __syncthreads();
    if (tid < 16) {
        double a0 = shs[0][tid].x + shs[1][tid].x;
        double a1 = shs[0][tid].y + shs[1][tid].y;
        double a2 = shs[0][tid].z + shs[1][tid].z;
        double a3 = shs[0][tid].w + shs[1][tid].w;
        psum[(size_t)blk * D + tid * 4 + 0] = a0;
        psum[(size_t)blk * D + tid * 4 + 1] = a1;
        psum[(size_t)blk * D + tid * 4 + 2] = a2;
        psum[(size_t)blk * D + tid * 4 + 3] = a3;
        double b0 = shq[0][tid].x + shq[1][tid].x;
        double b1 = shq[0][tid].y + shq[1][tid].y;
        double b2 = shq[0][tid].z + shq[1][tid].z;
        double b3 = shq[0][tid].w + shq[1][tid].w;
        psq[(size_t)blk * D + tid * 4 + 0] = b0;
        psq[(size_t)blk * D + tid * 4 + 1] = b1;
        psq[(size_t)blk * D + tid * 4 + 2] = b2;
        psq[(size_t)blk * D + tid * 4 + 3] = b3;
    }
}

__global__ void gcn_bn_kernel(const float* __restrict__ h, const int* __restrict__ idx,
                              const float* __restrict__ emb, float* __restrict__ t_out,
                              float* __restrict__ x_out,
                              double* __restrict__ psum, double* __restrict__ psq) {
    gcn_bn_body(h, idx, emb, t_out, x_out, psum, psq, blockIdx.x);
}

__global__ void gcn_bn_dual_kernel(const float* __restrict__ hA, const int* __restrict__ idxA,
                                   const float* __restrict__ embA, float* __restrict__ tA,
                                   float* __restrict__ xA,
                                   const float* __restrict__ hB, const int* __restrict__ idxB,
                                   const float* __restrict__ embB, float* __restrict__ tB,
                                   float* __restrict__ xB,
                                   double* __restrict__ psum, double* __restrict__ psq) {
    if (blockIdx.y == 0) gcn_bn_body(hA, idxA, embA, tA, xA, psum, psq, blockIdx.x);
    else                 gcn_bn_body(hB, idxB, embB, tB, xB, psum + (size_t)NPART * D,
                                     psq + (size_t)NPART * D, blockIdx.x);
}

// ---------------- BN reduce stage 1: 4000 partials -> 25 per bank ----------------
__device__ __forceinline__ void bn_reduce_body(const double* __restrict__ psum,
                                               const double* __restrict__ psq,
                                               double* __restrict__ rsum,
                                               double* __restrict__ rsq, int blk) {
    __shared__ double shs[4][D], shq2[4][D];
    int tid = threadIdx.x;
    int c = tid & 63, grp = tid >> 6;
    int base = blk * 160;
    double s = 0.0, qv = 0.0;
    #pragma unroll 4
    for (int p = grp; p < 160; p += 4) {
        s += psum[(size_t)(base + p) * D + c];
        qv += psq[(size_t)(base + p) * D + c];
    }
    shs[grp][c] = s; shq2[grp][c] = qv;
    __syncthreads();
    if (grp == 0) {
        rsum[(size_t)blk * D + c] = (shs[0][c] + shs[1][c]) + (shs[2][c] + shs[3][c]);
        rsq[(size_t)blk * D + c]  = (shq2[0][c] + shq2[1][c]) + (shq2[2][c] + shq2[3][c]);
    }
}

__global__ void bn_reduce_kernel(const double* __restrict__ psum, const double* __restrict__ psq,
                                 double* __restrict__ rsum, double* __restrict__ rsq) {
    size_t boff = (size_t)blockIdx.y * NPART * D;
    size_t roff = (size_t)blockIdx.y * NRED * D;
    bn_reduce_body(psum + boff, psq + boff, rsum + roff, rsq + roff, blockIdx.x);
}

// ---------------- BN finalize over NRED partials ----------------
__device__ __forceinline__ void bn_final_body(const double* __restrict__ rsum,
                                              const double* __restrict__ rsq,
                                              const float* __restrict__ g,
                                              const float* __restrict__ beta,
                                              float* __restrict__ ss_out) {
    __shared__ double shs[4][D], shq2[4][D];
    int tid = threadIdx.x;
    int c = tid & 63, grp = tid >> 6;
    double s = 0.0, qv = 0.0;
    for (int p = grp; p < NRED; p += 4) { s += rsum[(size_t)p * D + c]; qv += rsq[(size_t)p * D + c]; }
    shs[grp][c] = s; shq2[grp][c] = qv;
    __syncthreads();
    if (grp == 0) {
        double S = (shs[0][c] + shs[1][c]) + (shs[2][c] + shs[3][c]);
        double Q = (shq2[0][c] + shq2[1][c]) + (shq2[2][c] + shq2[3][c]);
        const double n = (double)NROWS;
        double mu = S / n;
        double var = Q / n - mu * mu;
        double inv = 1.0 / sqrt(var + 1e-5);
        double sc = (double)g[c] * inv;
        ss_out[c] = (float)sc;
        ss_out[D + c] = (float)((double)beta[c] - mu * sc);
    }
}

__global__ void bn_final_kernel(const double* __restrict__ rsum, const double* __restrict__ rsq,
                                const float* __restrict__ g, const float* __restrict__ beta,
                                float* __restrict__ ss_out) {
    bn_final_body(rsum, rsq, g, beta, ss_out);
}

__global__ void bn_final_dual_kernel(const double* __restrict__ rsum, const double* __restrict__ rsq,
                                     const float* __restrict__ gP, const float* __restrict__ beP,
                                     const float* __restrict__ gN, const float* __restrict__ beN,
                                     float* __restrict__ ssP, float* __restrict__ ssN) {
    size_t roff = (size_t)NRED * D;
    if (blockIdx.x == 0) bn_final_body(rsum, rsq, gP, beP, ssP);
    else                 bn_final_body(rsum + roff, rsq + roff, gN, beN, ssN);
}

// ---------------- fused mid: BN-apply + O=v@W_out + head GEMMs, O stays in LDS ----------------
__global__ void mid_fused_kernel(const float* __restrict__ t, const float* __restrict__ ss,
                                 const float* __restrict__ Wo, const float* __restrict__ bo,
                                 const float* __restrict__ Wp, const float* __restrict__ bp,
                                 const float* __restrict__ Wn, const float* __restrict__ bn_,
                                 float* __restrict__ outP, float* __restrict__ outN) {
    __shared__ float Wos[D * D];
    __shared__ float Wps[16 * D];
    __shared__ float Wns[48 * D];
    __shared__ float vs[8][D];
    __shared__ float os[8][D];
    int tid = threadIdx.x;
    for (int e = tid; e < D * D / 4; e += 256) ((float4*)Wos)[e] = ((const float4*)Wo)[e];
    for (int e = tid; e < 16 * D / 4; e += 256) ((float4*)Wps)[e] = ((const float4*)Wp)[e];
    for (int e = tid; e < 48 * D / 4; e += 256) ((float4*)Wns)[e] = ((const float4*)Wn)[e];
    int base = blockIdx.x * 8;
    for (int e = tid; e < 8 * D; e += 256) {
        int r = e >> 6, c = e & 63;
        float x = t[(size_t)(base + r) * D + c];
        vs[r][c] = fmaxf(fmaf(x, ss[c], ss[D + c]), 0.f);
    }
    __syncthreads();
    int lr = tid >> 6, c = tid & 63;
    #pragma unroll
    for (int rep = 0; rep < 2; ++rep) {
        int r = lr * 2 + rep;
        float acc = bo[c];
        #pragma unroll
        for (int k = 0; k < D; ++k) acc = fmaf(vs[r][k], Wos[k * D + c], acc);
        os[r][c] = acc;
    }
    __syncthreads();
    #pragma unroll
    for (int rep = 0; rep < 2; ++rep) {
        int r = lr * 2 + rep;
        float ap = bp[c];
        #pragma unroll
        for (int k = 0; k < 16; ++k) ap = fmaf(os[r][k], Wps[k * D + c], ap);
        float an = bn_[c];
        #pragma unroll
        for (int k = 0; k < 48; ++k) an = fmaf(os[r][16 + k], Wns[k * D + c], an);
        outP[(size_t)(base + r) * D + c] = ap;
        outN[(size_t)(base + r) * D + c] = an;
    }
}

// ---------------- fused heads: float4, 16 rows/block, sub-wave-16 reduction ----------------
__global__ void heads_kernel(const float* __restrict__ tP, const float* __restrict__ ssP,
                             const float* __restrict__ Wp, const float* __restrict__ bp,
                             float* __restrict__ outP,
                             const float* __restrict__ tN, const float* __restrict__ ssN,
                             const float* __restrict__ Wn, const float* __restrict__ bn_,
                             float* __restrict__ outN) {
    int tid = threadIdx.x;
    int rr = tid >> 4, q = tid & 15;
    int row = blockIdx.x * 16 + rr;
    if (blockIdx.y == 0) {
        float4 x4 = *(const float4*)(tP + (size_t)row * D + q * 4);
        float4 sc = *(const float4*)(ssP + q * 4);
        float4 of = *(const float4*)(ssP + D + q * 4);
        float b0 = fmaxf(fmaf(x4.x, sc.x, of.x), 0.f);
        float b1 = fmaxf(fmaf(x4.y, sc.y, of.y), 0.f);
        float b2 = fmaxf(fmaf(x4.z, sc.z, of.z), 0.f);
        float b3 = fmaxf(fmaf(x4.w, sc.w, of.w), 0.f);
        float4 w4 = *(const float4*)(Wp + q * 4);
        float p = b0 * w4.x + b1 * w4.y + b2 * w4.z + b3 * w4.w;
        p += __shfl_down(p, 8, 16);
        p += __shfl_down(p, 4, 16);
        p += __shfl_down(p, 2, 16);
        p += __shfl_down(p, 1, 16);
        if (q == 0) outP[row] = p + bp[0];
    } else {
        float4 x4 = *(const float4*)(tN + (size_t)row * D + q * 4);
        float4 sc = *(const float4*)(ssN + q * 4);
        float4 of = *(const float4*)(ssN + D + q * 4);
        float b0 = fmaxf(fmaf(x4.x, sc.x, of.x), 0.f);
        float b1 = fmaxf(fmaf(x4.y, sc.y, of.y), 0.f);
        float b2 = fmaxf(fmaf(x4.z, sc.z, of.z), 0.f);
        float b3 = fmaxf(fmaf(x4.w, sc.w, of.w), 0.f);
        const float4* wn4 = (const float4*)(Wn + q * 12);
        float4 wa = wn4[0], wb = wn4[1], wc = wn4[2];
        float p0 = b0 * wa.x + b1 * wa.w + b2 * wb.z + b3 * wc.y;
        float p1 = b0 * wa.y + b1 * wb.x + b2 * wb.w + b3 * wc.z;
        float p2 = b0 * wa.z + b1 * wb.y + b2 * wc.x + b3 * wc.w;
        p0 += __shfl_down(p0, 8, 16);  p0 += __shfl_down(p0, 4, 16);
        p0 += __shfl_down(p0, 2, 16);  p0 += __shfl_down(p0, 1, 16);
        p1 += __shfl_down(p1, 8, 16);  p1 += __shfl_down(p1, 4, 16);
        p1 += __shfl_down(p1, 2, 16);  p1 += __shfl_down(p1, 1, 16);
        p2 += __shfl_down(p2, 8, 16);  p2 += __shfl_down(p2, 4, 16);
        p2 += __shfl_down(p2, 2, 16);  p2 += __shfl_down(p2, 1, 16);
        if (q == 0) {
            outN[(size_t)row * 3 + 0] = p0 + bn_[0];
            outN[(size_t)row * 3 + 1] = p1 + bn_[1];
            outN[(size_t)row * 3 + 2] = p2 + bn_[2];
        }
    }
}

extern "C" void kernel_launch(void* const* d_in, const int* in_sizes, int n_in,
                              void* d_out, int out_size, void* d_ws, size_t ws_size,
                              hipStream_t stream) {
    const float* data    = (const float*)d_in[0];
    const float* mul_emb = (const float*)d_in[4];
    const float* phy_emb = (const float*)d_in[5];
    const float* net_emb = (const float*)d_in[6];
    const float* W_share = (const float*)d_in[7];
    const float* b_share = (const float*)d_in[8];
    const float* W_phy   = (const float*)d_in[9];
    const float* b_phy   = (const float*)d_in[10];
    const float* W_net   = (const float*)d_in[11];
    const float* b_net   = (const float*)d_in[12];
    const float* g_mul   = (const float*)d_in[13];
    const float* be_mul  = (const float*)d_in[14];
    const float* g_phy   = (const float*)d_in[15];
    const float* be_phy  = (const float*)d_in[16];
    const float* g_net   = (const float*)d_in[17];
    const float* be_net  = (const float*)d_in[18];
    const float* W_out   = (const float*)d_in[19];
    const float* b_out   = (const float*)d_in[20];
    const float* W_pout  = (const float*)d_in[21];
    const float* b_pout  = (const float*)d_in[22];
    const float* W_nout  = (const float*)d_in[23];
    const float* b_nout  = (const float*)d_in[24];

    float* outf = (float*)d_out;
    float* out_phy  = outf;            // 32000
    float* out_net  = outf + 32000;    // 96000
    float* out_idx  = outf + 128000;   // 20000 (idx_mul as floats)
    float* out_xnet = outf + 148000;   // 2048000
    float* out_xphy = outf + 2196000;  // 2048000

    char* ws = (char*)d_ws;
    size_t off = 0;
    auto alloc = [&](size_t bytes) -> void* {
        void* p = (void*)(ws + off);
        off += bytes;
        off = (off + 255) & ~(size_t)255;
        return p;
    };
    int* idxM = (int*)alloc(20000 * 4);
    int* idxP = (int*)alloc(20000 * 4);
    int* idxN = (int*)alloc(20000 * 4);
    double* inv_nrm = (double*)alloc(3000 * 8);
    double* psum = (double*)alloc(2 * (size_t)NPART * D * 8);   // 2 banks
    double* psq  = (double*)alloc(2 * (size_t)NPART * D * 8);
    double* rsum = (double*)alloc(2 * (size_t)NRED * D * 8);
    double* rsq  = (double*)alloc(2 * (size_t)NRED * D * 8);
    float* ssM = (float*)alloc(128 * 4);
    float* ssP = (float*)alloc(128 * 4);
    float* ssN = (float*)alloc(128 * 4);
    float* A  = (float*)alloc((size_t)NROWS * D * 4);  // h_share -> h_phy
    float* Bb = (float*)alloc((size_t)NROWS * D * 4);  // t_mul   -> h_net
    float* C  = (float*)alloc((size_t)NROWS * D * 4);  // t_phy
    float* Dd = (float*)alloc((size_t)NROWS * D * 4);  // t_net

    // 1. norms, then fused topk (3 graphs, 2 queries/block) + rowgemm60
    norms_kernel<<<dim3(4, 3), 256, 0, stream>>>(mul_emb, phy_emb, net_emb, inv_nrm);
    topk_gemm_kernel<<<5500, 256, 0, stream>>>(mul_emb, phy_emb, net_emb, inv_nrm,
                                               idxM, idxP, idxN, out_idx,
                                               data, W_share, b_share, A);

    // 2. mul path (gcn + inline BN partials; two-stage parallel finalize)
    gcn_bn_kernel<<<NPART, 128, 0, stream>>>(A, idxM, mul_emb, Bb, (float*)nullptr, psum, psq);
    bn_reduce_kernel<<<dim3(NRED, 1), 256, 0, stream>>>(psum, psq, rsum, rsq);
    bn_final_kernel<<<1, 256, 0, stream>>>(rsum, rsq, g_mul, be_mul, ssM);
    mid_fused_kernel<<<4000, 256, 0, stream>>>(Bb, ssM, W_out, b_out,
                                               W_phy, b_phy, W_net, b_net, A, Bb);

    // 3. phy / net heads
    gcn_bn_dual_kernel<<<dim3(NPART, 2), 128, 0, stream>>>(A, idxP, phy_emb, C, out_xphy,
                                                           Bb, idxN, net_emb, Dd, out_xnet,
                                                           psum, psq);
    bn_reduce_kernel<<<dim3(NRED, 2), 256, 0, stream>>>(psum, psq, rsum, rsq);
    bn_final_dual_kernel<<<2, 256, 0, stream>>>(rsum, rsq, g_phy, be_phy, g_net, be_net, ssP, ssN);
    heads_kernel<<<dim3(2000, 2), 256, 0, stream>>>(C, ssP, W_pout, b_pout, out_phy,
                                                    Dd, ssN, W_nout, b_nout, out_net);
}

// Round 16
// 146.374 us; speedup vs baseline: 3.1901x; 1.0244x over previous
//
#include <hip/hip_runtime.h>

#define NNODE 1000
#define D 64
#define K_TOP 20
#define NROWS 32000   // B*N = 32*1000
#define GCN_ROWS 8
#define NPART (NROWS / GCN_ROWS)   // 4000 BN partials
#define NRED 25                    // 4000 = 25*160
typedef unsigned long long ull;

// ---------------- inverse norms (f64) ----------------
__global__ void norms_kernel(const float* __restrict__ e0, const float* __restrict__ e1,
                             const float* __restrict__ e2, double* __restrict__ inv_nrm) {
    int g = blockIdx.y;
    const float* e = (g == 0) ? e0 : ((g == 1) ? e1 : e2);
    int j = blockIdx.x * 256 + threadIdx.x;
    if (j < NNODE) {
        double s = 0.0;
        #pragma unroll
        for (int k = 0; k < D; ++k) { double v = (double)e[j * D + k]; s += v * v; }
        inv_nrm[g * NNODE + j] = 1.0 / sqrt(s);
    }
}

__device__ __forceinline__ ull packkey(double cosv, int j) {
    ull b = (ull)__double_as_longlong(cosv);
    ull k = (b >> 63) ? ~b : (b | 0x8000000000000000ULL);
    return (k & ~1023ULL) | (ull)(1023 - j);
}

__device__ __forceinline__ int cnt20(const ull* pl, ull v) {
    const ulonglong2* p2 = (const ulonglong2*)pl;
    int cnt = 0;
    #pragma unroll
    for (int m = 0; m < 10; ++m) {
        ulonglong2 ab = p2[m];
        cnt += (ab.x > v) ? 1 : 0;
        cnt += (ab.y > v) ? 1 : 0;
    }
    return cnt;
}

// ---- fused: topk 2-queries/block (blocks 0..1499) + rowgemm60 (blocks 1500..5499) ----
// LDS overlay: winner lists + merge pyramid live inside query-0's dead key
// region (after its stage-1 count, enforced by a barrier), reused for q1.
// Total LDS = 17.28 KB -> 8 blocks/CU (32 waves, vs R15's 6 blocks/49%).
// Dot FMA order, quad-fold, pack, count and merge compare semantics are
// byte-identical to the verified R15 kernel -> bit-identical indices.
__global__ void __launch_bounds__(256, 2)
topk_gemm_kernel(const float* __restrict__ e0, const float* __restrict__ e1,
                 const float* __restrict__ e2, const double* __restrict__ inv_nrm,
                 int* __restrict__ idxM, int* __restrict__ idxP,
                 int* __restrict__ idxN, float* __restrict__ idxf_out,
                 const float* __restrict__ X, const float* __restrict__ W,
                 const float* __restrict__ bias, float* __restrict__ A) {
    __shared__ __align__(16) char smem[17280];
    int blk = blockIdx.x;
    int tid = threadIdx.x;

    if (blk < 1500) {
        float* srow = (float*)smem;                  // 512 B (2 query rows)
        ull* skey  = (ull*)(smem + 512);             // 2*1024*8 = 16384 -> ends 16896
        // overlays: inside skey[0..664) bytes — dead after the current query's count
        ull* swv   = (ull*)(smem + 512);             // 320*8 = 2560
        ull* m8    = (ull*)(smem + 3072);            // 160*8 = 1280
        ull* m4    = (ull*)(smem + 4352);            // 80*8  = 640
        ull* m2    = (ull*)(smem + 4992);            // 40*8  = 320 -> ends 5312

        int g = blk / 500;
        int i0 = (blk - g * 500) * 2;                // queries i0, i0+1
        const float* emb = (g == 0) ? e0 : ((g == 1) ? e1 : e2);
        int* idx_out = (g == 0) ? idxM : ((g == 1) ? idxP : idxN);
        const double* inv = inv_nrm + g * NNODE;

        int w = tid >> 6, l = tid & 63;
        int rowq = tid >> 2;
        int s = tid & 3;

        if (tid < 2 * D) srow[tid] = emb[(i0 + (tid >> 6)) * D + (tid & 63)];
        __syncthreads();

        double inv_i0 = inv[i0];
        double inv_i1 = inv[i0 + 1];
        const float4* sr0 = (const float4*)srow + s * 4;
        const float4* sr1 = (const float4*)(srow + D) + s * 4;

        // dot phase: 16 coalesced passes; candidate loaded once, 2 queries
        #pragma unroll 2
        for (int p = 0; p < 16; ++p) {
            int j = p * 64 + rowq;
            int jc = (j < NNODE) ? j : 0;
            const float4* ej = (const float4*)(emb + (size_t)jc * D) + s * 4;
            double a0 = 0.0, a1 = 0.0;
            #pragma unroll
            for (int q = 0; q < 4; ++q) {
                float4 v = ej[q];
                float4 r0 = sr0[q];
                float4 r1 = sr1[q];
                a0 = fma((double)v.x, (double)r0.x, a0);
                a0 = fma((double)v.y, (double)r0.y, a0);
                a0 = fma((double)v.z, (double)r0.z, a0);
                a0 = fma((double)v.w, (double)r0.w, a0);
                a1 = fma((double)v.x, (double)r1.x, a1);
                a1 = fma((double)v.y, (double)r1.y, a1);
                a1 = fma((double)v.z, (double)r1.z, a1);
                a1 = fma((double)v.w, (double)r1.w, a1);
            }
            a0 += __shfl_xor(a0, 1, 64);  a0 += __shfl_xor(a0, 2, 64);
            a1 += __shfl_xor(a1, 1, 64);  a1 += __shfl_xor(a1, 2, 64);
            if (s == 0) {
                double invj = inv[jc];
                bool ok = (j < NNODE);
                skey[j]        = ok ? packkey(a0 * inv_i0 * invj, j) : 0ULL;
                skey[1024 + j] = ok ? packkey(a1 * inv_i1 * invj, j) : 0ULL;
            }
        }
        __syncthreads();

        // per query: stage-1 chunk rank -> (barrier) -> winners into overlay
        //            -> (barrier) -> 4-level tournament merge -> output
        for (int qq = 0; qq < 2; ++qq) {
            const ull* sq = skey + qq * 1024;
            int i = i0 + qq;
            const ulonglong2* base = (const ulonglong2*)(sq + (w << 8));
            ull k0 = sq[(w << 8) + l];
            ull k1 = sq[(w << 8) + 64 + l];
            ull k2 = sq[(w << 8) + 128 + l];
            ull k3 = sq[(w << 8) + 192 + l];
            int n0 = 0, n1 = 0, n2 = 0, n3 = 0;
            #pragma unroll 8
            for (int m = 0; m < 32; ++m) {
                ulonglong2 a0 = base[m];
                ulonglong2 a1 = base[32 + m];
                ulonglong2 a2 = base[64 + m];
                ulonglong2 a3 = base[96 + m];
                n0 += (a0.x > k0) ? 1 : 0;  n0 += (a0.y > k0) ? 1 : 0;
                n1 += (a1.x > k1) ? 1 : 0;  n1 += (a1.y > k1) ? 1 : 0;
                n2 += (a2.x > k2) ? 1 : 0;  n2 += (a2.y > k2) ? 1 : 0;
                n3 += (a3.x > k3) ? 1 : 0;  n3 += (a3.y > k3) ? 1 : 0;
            }
            __syncthreads();    // all reads of this query's keys done -> overlay safe
            if (n0 < K_TOP) swv[((w << 2) + 0) * K_TOP + n0] = k0;
            if (n1 < K_TOP) swv[((w << 2) + 1) * K_TOP + n1] = k1;
            if (n2 < K_TOP) swv[((w << 2) + 2) * K_TOP + n2] = k2;
            if (n3 < K_TOP) swv[((w << 2) + 3) * K_TOP + n3] = k3;
            __syncthreads();
            {
                int e = tid;
                int lw = e / K_TOP, r = e % K_TOP;
                ull v = swv[e];
                int rank = r + cnt20(swv + (lw ^ 1) * K_TOP, v);
                if (rank < K_TOP) m8[(lw >> 1) * K_TOP + rank] = v;
                if (tid < 64) {
                    int e2 = 256 + tid;
                    int lw2 = e2 / K_TOP, r2 = e2 % K_TOP;
                    ull v2 = swv[e2];
                    int rank2 = r2 + cnt20(swv + (lw2 ^ 1) * K_TOP, v2);
                    if (rank2 < K_TOP) m8[(lw2 >> 1) * K_TOP + rank2] = v2;
                }
            }
            __syncthreads();
            if (tid < 160) {
                int lw = tid / K_TOP, r = tid % K_TOP;
                ull v = m8[tid];
                int rank = r + cnt20(m8 + (lw ^ 1) * K_TOP, v);
                if (rank < K_TOP) m4[(lw >> 1) * K_TOP + rank] = v;
            }
            __syncthreads();
            if (tid < 80) {
                int lw = tid / K_TOP, r = tid % K_TOP;
                ull v = m4[tid];
                int rank = r + cnt20(m4 + (lw ^ 1) * K_TOP, v);
                if (rank < K_TOP) m2[(lw >> 1) * K_TOP + rank] = v;
            }
            __syncthreads();
            if (tid < 40) {
                int lw = tid / K_TOP, r = tid % K_TOP;
                ull v = m2[tid];
                int rank = r + cnt20(m2 + (lw ^ 1) * K_TOP, v);
                if (rank < K_TOP) {
                    int id = 1023 - (int)(v & 1023ULL);
                    idx_out[i * K_TOP + rank] = id;
                    if (g == 0) idxf_out[i * K_TOP + rank] = (float)id;
                }
            }
            __syncthreads();   // m2 consumed before next query reuses overlay
        }
    } else {
        const int K = 60;
        float* Ws = (float*)smem;               // 15360 B
        float* xs = (float*)(smem + 15360);     // 1920 B -> 17280 total
        int rb = blk - 1500;
        for (int e = tid; e < K * D; e += 256) Ws[e] = W[e];
        int base_row = rb * 8;
        for (int e = tid; e < 8 * K; e += 256) {
            int r = e / K, k = e % K;
            xs[r * K + k] = X[(size_t)(base_row + r) * K + k];
        }
        __syncthreads();
        int lr = tid >> 6, c = tid & 63;
        #pragma unroll
        for (int rep = 0; rep < 2; ++rep) {
            int r = lr * 2 + rep;
            float acc = bias[c];
            #pragma unroll
            for (int k = 0; k < K; ++k) acc = fmaf(xs[r * K + k], Ws[k * D + c], acc);
            A[(size_t)(base_row + r) * D + c] = acc;
        }
    }
}

// ---------------- GCN gather-mean-relu (float4) + inline BN partial sums ----------------
__device__ __forceinline__ void gcn_bn_body(const float* __restrict__ h, const int* __restrict__ idx,
                                            const float* __restrict__ emb, float* __restrict__ t_out,
                                            float* __restrict__ x_out,
                                            double* __restrict__ psum, double* __restrict__ psq,
                                            int blk) {
    __shared__ int nbrs[GCN_ROWS][K_TOP];
    __shared__ double4 shs[2][16], shq[2][16];
    int tid = threadIdx.x;              // 0..127
    int rr = tid >> 4, q = tid & 15;
    int b = blk & 31;                   // batch (b%8 == blk%8 -> XCD affinity)
    int g = blk >> 5;                   // node group 0..124
    int base_node = g * GCN_ROWS;
    for (int e = tid; e < GCN_ROWS * K_TOP; e += 128) {
        int r2 = e / K_TOP, tt = e % K_TOP;
        nbrs[r2][tt] = idx[(base_node + r2) * K_TOP + tt];
    }
    __syncthreads();
    int i = base_node + rr;
    int row = b * NNODE + i;
    const float* hb = h + (size_t)b * NNODE * D;
    float4 s4 = make_float4(0.f, 0.f, 0.f, 0.f);
    #pragma unroll
    for (int t = 0; t < K_TOP; ++t) {
        float4 v = *(const float4*)(hb + (size_t)nbrs[rr][t] * D + q * 4);
        s4.x += v.x; s4.y += v.y; s4.z += v.z; s4.w += v.w;
    }
    const float inv20 = 1.0f / 20.0f;
    float4 y4;
    y4.x = fmaxf(s4.x * inv20, 0.f);
    y4.y = fmaxf(s4.y * inv20, 0.f);
    y4.z = fmaxf(s4.z * inv20, 0.f);
    y4.w = fmaxf(s4.w * inv20, 0.f);
    if (x_out) *(float4*)(x_out + (size_t)row * D + q * 4) = y4;
    float4 e4 = *(const float4*)(emb + (size_t)i * D + q * 4);
    float4 t4 = make_float4(y4.x * e4.x, y4.y * e4.y, y4.z * e4.z, y4.w * e4.w);
    *(float4*)(t_out + (size_t)row * D + q * 4) = t4;

    double s0 = t4.x, s1 = t4.y, s2 = t4.z, s3 = t4.w;
    double q0 = s0 * s0, q1 = s1 * s1, q2 = s2 * s2, q3 = s3 * s3;
    s0 += __shfl_xor(s0, 16, 64);  s0 += __shfl_xor(s0, 32, 64);
    s1 += __shfl_xor(s1, 16, 64);  s1 += __shfl_xor(s1, 32, 64);
    s2 += __shfl_xor(s2, 16, 64);  s2 += __shfl_xor(s2, 32, 64);
    s3 += __shfl_xor(s3, 16, 64);  s3 += __shfl_xor(s3, 32, 64);
    q0 += __shfl_xor(q0, 16, 64);  q0 += __shfl_xor(q0, 32, 64);
    q1 += __shfl_xor(q1, 16, 64);  q1 += __shfl_xor(q1, 32, 64);
    q2 += __shfl_xor(q2, 16, 64);  q2 += __shfl_xor(q2, 32, 64);
    q3 += __shfl_xor(q3, 16, 64);  q3 += __shfl_xor(q3, 32, 64);
    int wv = tid >> 6;
    if (((tid >> 4) & 3) == 0) {
        shs[wv][q] = make_double4(s0, s1, s2, s3);
        shq[wv][q] = make_double4(q0, q1, q2, q3);
    }
    __syncthreads();
    if (tid < 16) {
        double a0 = shs[0][tid].x + shs[1][tid].x;
        double a1 = shs[0][tid].y + shs[1][tid].y;
        double a2 = shs[0][tid].z + shs[1][tid].z;
        double a3 = shs[0][tid].w + shs[1][tid].w;
        psum[(size_t)blk * D + tid * 4 + 0] = a0;
        psum[(size_t)blk * D + tid * 4 + 1] = a1;
        psum[(size_t)blk * D + tid * 4 + 2] = a2;
        psum[(size_t)blk * D + tid * 4 + 3] = a3;
        double b0 = shq[0][tid].x + shq[1][tid].x;
        double b1 = shq[0][tid].y + shq[1][tid].y;
        double b2 = shq[0][tid].z + shq[1][tid].z;
        double b3 = shq[0][tid].w + shq[1][tid].w;
        psq[(size_t)blk * D + tid * 4 + 0] = b0;
        psq[(size_t)blk * D + tid * 4 + 1] = b1;
        psq[(size_t)blk * D + tid * 4 + 2] = b2;
        psq[(size_t)blk * D + tid * 4 + 3] = b3;
    }
}

__global__ void gcn_bn_kernel(const float* __restrict__ h, const int* __restrict__ idx,
                              const float* __restrict__ emb, float* __restrict__ t_out,
                              float* __restrict__ x_out,
                              double* __restrict__ psum, double* __restrict__ psq) {
    gcn_bn_body(h, idx, emb, t_out, x_out, psum, psq, blockIdx.x);
}

__global__ void gcn_bn_dual_kernel(const float* __restrict__ hA, const int* __restrict__ idxA,
                                   const float* __restrict__ embA, float* __restrict__ tA,
                                   float* __restrict__ xA,
                                   const float* __restrict__ hB, const int* __restrict__ idxB,
                                   const float* __restrict__ embB, float* __restrict__ tB,
                                   float* __restrict__ xB,
                                   double* __restrict__ psum, double* __restrict__ psq) {
    if (blockIdx.y == 0) gcn_bn_body(hA, idxA, embA, tA, xA, psum, psq, blockIdx.x);
    else                 gcn_bn_body(hB, idxB, embB, tB, xB, psum + (size_t)NPART * D,
                                     psq + (size_t)NPART * D, blockIdx.x);
}

// ---------------- BN reduce stage 1: 4000 partials -> 25 per bank ----------------
__device__ __forceinline__ void bn_reduce_body(const double* __restrict__ psum,
                                               const double* __restrict__ psq,
                                               double* __restrict__ rsum,
                                               double* __restrict__ rsq, int blk) {
    __shared__ double shs[4][D], shq2[4][D];
    int tid = threadIdx.x;
    int c = tid & 63, grp = tid >> 6;
    int base = blk * 160;
    double s = 0.0, qv = 0.0;
    #pragma unroll 4
    for (int p = grp; p < 160; p += 4) {
        s += psum[(size_t)(base + p) * D + c];
        qv += psq[(size_t)(base + p) * D + c];
    }
    shs[grp][c] = s; shq2[grp][c] = qv;
    __syncthreads();
    if (grp == 0) {
        rsum[(size_t)blk * D + c] = (shs[0][c] + shs[1][c]) + (shs[2][c] + shs[3][c]);
        rsq[(size_t)blk * D + c]  = (shq2[0][c] + shq2[1][c]) + (shq2[2][c] + shq2[3][c]);
    }
}

__global__ void bn_reduce_kernel(const double* __restrict__ psum, const double* __restrict__ psq,
                                 double* __restrict__ rsum, double* __restrict__ rsq) {
    size_t boff = (size_t)blockIdx.y * NPART * D;
    size_t roff = (size_t)blockIdx.y * NRED * D;
    bn_reduce_body(psum + boff, psq + boff, rsum + roff, rsq + roff, blockIdx.x);
}

// ---------------- BN finalize over NRED partials ----------------
__device__ __forceinline__ void bn_final_body(const double* __restrict__ rsum,
                                              const double* __restrict__ rsq,
                                              const float* __restrict__ g,
                                              const float* __restrict__ beta,
                                              float* __restrict__ ss_out) {
    __shared__ double shs[4][D], shq2[4][D];
    int tid = threadIdx.x;
    int c = tid & 63, grp = tid >> 6;
    double s = 0.0, qv = 0.0;
    for (int p = grp; p < NRED; p += 4) { s += rsum[(size_t)p * D + c]; qv += rsq[(size_t)p * D + c]; }
    shs[grp][c] = s; shq2[grp][c] = qv;
    __syncthreads();
    if (grp == 0) {
        double S = (shs[0][c] + shs[1][c]) + (shs[2][c] + shs[3][c]);
        double Q = (shq2[0][c] + shq2[1][c]) + (shq2[2][c] + shq2[3][c]);
        const double n = (double)NROWS;
        double mu = S / n;
        double var = Q / n - mu * mu;
        double inv = 1.0 / sqrt(var + 1e-5);
        double sc = (double)g[c] * inv;
        ss_out[c] = (float)sc;
        ss_out[D + c] = (float)((double)beta[c] - mu * sc);
    }
}

__global__ void bn_final_kernel(const double* __restrict__ rsum, const double* __restrict__ rsq,
                                const float* __restrict__ g, const float* __restrict__ beta,
                                float* __restrict__ ss_out) {
    bn_final_body(rsum, rsq, g, beta, ss_out);
}

__global__ void bn_final_dual_kernel(const double* __restrict__ rsum, const double* __restrict__ rsq,
                                     const float* __restrict__ gP, const float* __restrict__ beP,
                                     const float* __restrict__ gN, const float* __restrict__ beN,
                                     float* __restrict__ ssP, float* __restrict__ ssN) {
    size_t roff = (size_t)NRED * D;
    if (blockIdx.x == 0) bn_final_body(rsum, rsq, gP, beP, ssP);
    else                 bn_final_body(rsum + roff, rsq + roff, gN, beN, ssN);
}

// ---------------- fused mid: BN-apply + O=v@W_out + head GEMMs, O stays in LDS ----------------
__global__ void mid_fused_kernel(const float* __restrict__ t, const float* __restrict__ ss,
                                 const float* __restrict__ Wo, const float* __restrict__ bo,
                                 const float* __restrict__ Wp, const float* __restrict__ bp,
                                 const float* __restrict__ Wn, const float* __restrict__ bn_,
                                 float* __restrict__ outP, float* __restrict__ outN) {
    __shared__ float Wos[D * D];
    __shared__ float Wps[16 * D];
    __shared__ float Wns[48 * D];
    __shared__ float vs[8][D];
    __shared__ float os[8][D];
    int tid = threadIdx.x;
    for (int e = tid; e < D * D / 4; e += 256) ((float4*)Wos)[e] = ((const float4*)Wo)[e];
    for (int e = tid; e < 16 * D / 4; e += 256) ((float4*)Wps)[e] = ((const float4*)Wp)[e];
    for (int e = tid; e < 48 * D / 4; e += 256) ((float4*)Wns)[e] = ((const float4*)Wn)[e];
    int base = blockIdx.x * 8;
    for (int e = tid; e < 8 * D; e += 256) {
        int r = e >> 6, c = e & 63;
        float x = t[(size_t)(base + r) * D + c];
        vs[r][c] = fmaxf(fmaf(x, ss[c], ss[D + c]), 0.f);
    }
    __syncthreads();
    int lr = tid >> 6, c = tid & 63;
    #pragma unroll
    for (int rep = 0; rep < 2; ++rep) {
        int r = lr * 2 + rep;
        float acc = bo[c];
        #pragma unroll
        for (int k = 0; k < D; ++k) acc = fmaf(vs[r][k], Wos[k * D + c], acc);
        os[r][c] = acc;
    }
    __syncthreads();
    #pragma unroll
    for (int rep = 0; rep < 2; ++rep) {
        int r = lr * 2 + rep;
        float ap = bp[c];
        #pragma unroll
        for (int k = 0; k < 16; ++k) ap = fmaf(os[r][k], Wps[k * D + c], ap);
        float an = bn_[c];
        #pragma unroll
        for (int k = 0; k < 48; ++k) an = fmaf(os[r][16 + k], Wns[k * D + c], an);
        outP[(size_t)(base + r) * D + c] = ap;
        outN[(size_t)(base + r) * D + c] = an;
    }
}

// ---------------- fused heads: float4, 16 rows/block, sub-wave-16 reduction ----------------
__global__ void heads_kernel(const float* __restrict__ tP, const float* __restrict__ ssP,
                             const float* __restrict__ Wp, const float* __restrict__ bp,
                             float* __restrict__ outP,
                             const float* __restrict__ tN, const float* __restrict__ ssN,
                             const float* __restrict__ Wn, const float* __restrict__ bn_,
                             float* __restrict__ outN) {
    int tid = threadIdx.x;
    int rr = tid >> 4, q = tid & 15;
    int row = blockIdx.x * 16 + rr;
    if (blockIdx.y == 0) {
        float4 x4 = *(const float4*)(tP + (size_t)row * D + q * 4);
        float4 sc = *(const float4*)(ssP + q * 4);
        float4 of = *(const float4*)(ssP + D + q * 4);
        float b0 = fmaxf(fmaf(x4.x, sc.x, of.x), 0.f);
        float b1 = fmaxf(fmaf(x4.y, sc.y, of.y), 0.f);
        float b2 = fmaxf(fmaf(x4.z, sc.z, of.z), 0.f);
        float b3 = fmaxf(fmaf(x4.w, sc.w, of.w), 0.f);
        float4 w4 = *(const float4*)(Wp + q * 4);
        float p = b0 * w4.x + b1 * w4.y + b2 * w4.z + b3 * w4.w;
        p += __shfl_down(p, 8, 16);
        p += __shfl_down(p, 4, 16);
        p += __shfl_down(p, 2, 16);
        p += __shfl_down(p, 1, 16);
        if (q == 0) outP[row] = p + bp[0];
    } else {
        float4 x4 = *(const float4*)(tN + (size_t)row * D + q * 4);
        float4 sc = *(const float4*)(ssN + q * 4);
        float4 of = *(const float4*)(ssN + D + q * 4);
        float b0 = fmaxf(fmaf(x4.x, sc.x, of.x), 0.f);
        float b1 = fmaxf(fmaf(x4.y, sc.y, of.y), 0.f);
        float b2 = fmaxf(fmaf(x4.z, sc.z, of.z), 0.f);
        float b3 = fmaxf(fmaf(x4.w, sc.w, of.w), 0.f);
        const float4* wn4 = (const float4*)(Wn + q * 12);
        float4 wa = wn4[0], wb = wn4[1], wc = wn4[2];
        float p0 = b0 * wa.x + b1 * wa.w + b2 * wb.z + b3 * wc.y;
        float p1 = b0 * wa.y + b1 * wb.x + b2 * wb.w + b3 * wc.z;
        float p2 = b0 * wa.z + b1 * wb.y + b2 * wc.x + b3 * wc.w;
        p0 += __shfl_down(p0, 8, 16);  p0 += __shfl_down(p0, 4, 16);
        p0 += __shfl_down(p0, 2, 16);  p0 += __shfl_down(p0, 1, 16);
        p1 += __shfl_down(p1, 8, 16);  p1 += __shfl_down(p1, 4, 16);
        p1 += __shfl_down(p1, 2, 16);  p1 += __shfl_down(p1, 1, 16);
        p2 += __shfl_down(p2, 8, 16);  p2 += __shfl_down(p2, 4, 16);
        p2 += __shfl_down(p2, 2, 16);  p2 += __shfl_down(p2, 1, 16);
        if (q == 0) {
            outN[(size_t)row * 3 + 0] = p0 + bn_[0];
            outN[(size_t)row * 3 + 1] = p1 + bn_[1];
            outN[(size_t)row * 3 + 2] = p2 + bn_[2];
        }
    }
}

extern "C" void kernel_launch(void* const* d_in, const int* in_sizes, int n_in,
                              void* d_out, int out_size, void* d_ws, size_t ws_size,
                              hipStream_t stream) {
    const float* data    = (const float*)d_in[0];
    const float* mul_emb = (const float*)d_in[4];
    const float* phy_emb = (const float*)d_in[5];
    const float* net_emb = (const float*)d_in[6];
    const float* W_share = (const float*)d_in[7];
    const float* b_share = (const float*)d_in[8];
    const float* W_phy   = (const float*)d_in[9];
    const float* b_phy   = (const float*)d_in[10];
    const float* W_net   = (const float*)d_in[11];
    const float* b_net   = (const float*)d_in[12];
    const float* g_mul   = (const float*)d_in[13];
    const float* be_mul  = (const float*)d_in[14];
    const float* g_phy   = (const float*)d_in[15];
    const float* be_phy  = (const float*)d_in[16];
    const float* g_net   = (const float*)d_in[17];
    const float* be_net  = (const float*)d_in[18];
    const float* W_out   = (const float*)d_in[19];
    const float* b_out   = (const float*)d_in[20];
    const float* W_pout  = (const float*)d_in[21];
    const float* b_pout  = (const float*)d_in[22];
    const float* W_nout  = (const float*)d_in[23];
    const float* b_nout  = (const float*)d_in[24];

    float* outf = (float*)d_out;
    float* out_phy  = outf;            // 32000
    float* out_net  = outf + 32000;    // 96000
    float* out_idx  = outf + 128000;   // 20000 (idx_mul as floats)
    float* out_xnet = outf + 148000;   // 2048000
    float* out_xphy = outf + 2196000;  // 2048000

    char* ws = (char*)d_ws;
    size_t off = 0;
    auto alloc = [&](size_t bytes) -> void* {
        void* p = (void*)(ws + off);
        off += bytes;
        off = (off + 255) & ~(size_t)255;
        return p;
    };
    int* idxM = (int*)alloc(20000 * 4);
    int* idxP = (int*)alloc(20000 * 4);
    int* idxN = (int*)alloc(20000 * 4);
    double* inv_nrm = (double*)alloc(3000 * 8);
    double* psum = (double*)alloc(2 * (size_t)NPART * D * 8);   // 2 banks
    double* psq  = (double*)alloc(2 * (size_t)NPART * D * 8);
    double* rsum = (double*)alloc(2 * (size_t)NRED * D * 8);
    double* rsq  = (double*)alloc(2 * (size_t)NRED * D * 8);
    float* ssM = (float*)alloc(128 * 4);
    float* ssP = (float*)alloc(128 * 4);
    float* ssN = (float*)alloc(128 * 4);
    float* A  = (float*)alloc((size_t)NROWS * D * 4);  // h_share -> h_phy
    float* Bb = (float*)alloc((size_t)NROWS * D * 4);  // t_mul   -> h_net
    float* C  = (float*)alloc((size_t)NROWS * D * 4);  // t_phy
    float* Dd = (float*)alloc((size_t)NROWS * D * 4);  // t_net

    // 1. norms, then fused topk (3 graphs, 2 queries/block) + rowgemm60
    norms_kernel<<<dim3(4, 3), 256, 0, stream>>>(mul_emb, phy_emb, net_emb, inv_nrm);
    topk_gemm_kernel<<<5500, 256, 0, stream>>>(mul_emb, phy_emb, net_emb, inv_nrm,
                                               idxM, idxP, idxN, out_idx,
                                               data, W_share, b_share, A);

    // 2. mul path (gcn + inline BN partials; two-stage parallel finalize)
    gcn_bn_kernel<<<NPART, 128, 0, stream>>>(A, idxM, mul_emb, Bb, (float*)nullptr, psum, psq);
    bn_reduce_kernel<<<dim3(NRED, 1), 256, 0, stream>>>(psum, psq, rsum, rsq);
    bn_final_kernel<<<1, 256, 0, stream>>>(rsum, rsq, g_mul, be_mul, ssM);
    mid_fused_kernel<<<4000, 256, 0, stream>>>(Bb, ssM, W_out, b_out,
                                               W_phy, b_phy, W_net, b_net, A, Bb);

    // 3. phy / net heads
    gcn_bn_dual_kernel<<<dim3(NPART, 2), 128, 0, stream>>>(A, idxP, phy_emb, C, out_xphy,
                                                           Bb, idxN, net_emb, Dd, out_xnet,
                                                           psum, psq);
    bn_reduce_kernel<<<dim3(NRED, 2), 256, 0, stream>>>(psum, psq, rsum, rsq);
    bn_final_dual_kernel<<<2, 256, 0, stream>>>(rsum, rsq, g_phy, be_phy, g_net, be_net, ssP, ssN);
    heads_kernel<<<dim3(2000, 2), 256, 0, stream>>>(C, ssP, W_pout, b_pout, out_phy,
                                                    Dd, ssN, W_nout, b_nout, out_net);
}